// Round 1
// baseline (20951.573 us; speedup 1.0000x reference)
//
#include <hip/hip_runtime.h>
#include <math.h>

#define NN 50000
#define EE 800000
#define FF 32
#define HH 64
#define GG 2048
#define NLAYERS 4
#define EPSF 1e-6f

__device__ __forceinline__ float elu_f(float x){ return x > 0.0f ? x : __expf(x) - 1.0f; }

// ---------------- edge geometry + in-degree ----------------
__global__ __launch_bounds__(256) void k_edgegeo(
    const int* __restrict__ ei, const float* __restrict__ pos,
    float* __restrict__ dedge, float* __restrict__ uvec, float* __restrict__ counts)
{
    int e = blockIdx.x*256 + threadIdx.x;
    if (e >= EE) return;
    int src = ei[e], dst = ei[EE+e];
    float dx = pos[dst*3+0]-pos[src*3+0];
    float dy = pos[dst*3+1]-pos[src*3+1];
    float dz = pos[dst*3+2]-pos[src*3+2];
    float d = sqrtf(dx*dx+dy*dy+dz*dz+EPSF);
    dedge[e] = d;
    float inv = 1.0f/d;
    uvec[e*3+0]=dx*inv; uvec[e*3+1]=dy*inv; uvec[e*3+2]=dz*inv;
    atomicAdd(&counts[dst], 1.0f);
}

// ---------------- node embedding ----------------
__global__ __launch_bounds__(256) void k_embed(
    const float* __restrict__ x, const float* __restrict__ pos,
    const float* __restrict__ W_es, const float* __restrict__ b_es,
    const float* __restrict__ W_ev,
    float* __restrict__ ns, float* __restrict__ nv)
{
    int tid = blockIdx.x*256 + threadIdx.x;
    if (tid >= NN*FF) return;
    int n = tid >> 5, f = tid & 31;
    float x0=x[n*5+0], x1=x[n*5+1], x2=x[n*5+2], x3=x[n*5+3], x4=x[n*5+4];
    float s  = b_es[f] + x0*W_es[f] + x1*W_es[32+f] + x2*W_es[64+f] + x3*W_es[96+f] + x4*W_es[128+f];
    float vm =           x0*W_ev[f] + x1*W_ev[32+f] + x2*W_ev[64+f] + x3*W_ev[96+f] + x4*W_ev[128+f];
    ns[tid] = s;
    nv[n*96+f*3+0] = vm*pos[n*3+0];
    nv[n*96+f*3+1] = vm*pos[n*3+1];
    nv[n*96+f*3+2] = vm*pos[n*3+2];
}

// ---------------- W2 transpose: [l][k(64)][j(96)] -> [l][j(96)][k(64)] ----------------
__global__ __launch_bounds__(256) void k_transpose(const float* __restrict__ W2, float* __restrict__ W2T)
{
    int tid = blockIdx.x*256 + threadIdx.x;
    if (tid >= NLAYERS*6144) return;
    int l = tid / 6144; int r = tid - l*6144;
    int j = r >> 6; int k = r & 63;
    W2T[l*6144 + j*64 + k] = W2[l*6144 + k*96 + j];
}

// ---------------- per-edge message + scatter ----------------
__global__ __launch_bounds__(256) void k_msg(
    const int* __restrict__ ei, const float* __restrict__ dedge,
    const float* __restrict__ uvec, const float* __restrict__ eattr,
    const float* __restrict__ W1l, const float* __restrict__ b1l,
    const float* __restrict__ W2Tl, const float* __restrict__ b2l,
    const float* __restrict__ ns, const float* __restrict__ nv,
    float* __restrict__ acc_s, float* __restrict__ acc_v)
{
    int e = blockIdx.x*256 + threadIdx.x;
    if (e >= EE) return;
    int src = ei[e], dst = ei[EE+e];
    float ein0 = dedge[e];
    float ein1 = eattr[e*4+0], ein2 = eattr[e*4+1], ein3 = eattr[e*4+2], ein4 = eattr[e*4+3];

    float hidden[HH];
    #pragma unroll
    for (int k=0;k<HH;k++){
        float a = b1l[k] + ein0*W1l[k] + ein1*W1l[64+k] + ein2*W1l[128+k]
                         + ein3*W1l[192+k] + ein4*W1l[256+k];
        hidden[k] = elu_f(a);
    }
    float u0 = uvec[e*3+0], u1 = uvec[e*3+1], u2 = uvec[e*3+2];
    const float* sb = ns + (long long)src*32;
    const float* vb = nv + (long long)src*96;
    float* as_b = acc_s + (long long)dst*32;
    float* av_b = acc_v + (long long)dst*96;

    for (int f=0; f<FF; f++){
        const float* c0 = W2Tl + f*64;
        const float* c1 = W2Tl + (f+32)*64;
        const float* c2 = W2Tl + (f+64)*64;
        float gs = b2l[f], gv = b2l[32+f], gsv = b2l[64+f];
        #pragma unroll
        for (int k=0;k<HH;k++){
            gs  += hidden[k]*c0[k];
            gv  += hidden[k]*c1[k];
            gsv += hidden[k]*c2[k];
        }
        float ssrc = sb[f];
        float v0 = vb[f*3+0], v1 = vb[f*3+1], v2 = vb[f*3+2];
        float ms = gs*ssrc;
        float c  = gsv*ssrc;
        atomicAdd(as_b+f,       ms);
        atomicAdd(av_b+f*3+0,   gv*v0 + c*u0);
        atomicAdd(av_b+f*3+1,   gv*v1 + c*u1);
        atomicAdd(av_b+f*3+2,   gv*v2 + c*u2);
    }
}

// ---------------- node update (Ws/Wv apply, residual, re-zero acc) ----------------
__global__ __launch_bounds__(256) void k_nodeupd(
    const float* __restrict__ counts,
    const float* __restrict__ Wsl, const float* __restrict__ Wvl,
    float* __restrict__ acc_s, float* __restrict__ acc_v,
    float* __restrict__ ns, float* __restrict__ nv)
{
    int tid = blockIdx.x*256 + threadIdx.x;
    int n = tid >> 5;
    int g = tid & 31;
    if (n >= NN) return;
    float inv = 1.0f / fmaxf(counts[n], 1.0f);
    float asv = acc_s[n*32+g]*inv;
    float av0 = acc_v[n*96+g*3+0]*inv;
    float av1 = acc_v[n*96+g*3+1]*inv;
    float av2 = acc_v[n*96+g*3+2]*inv;
    acc_s[n*32+g] = 0.0f;
    acc_v[n*96+g*3+0]=0.0f; acc_v[n*96+g*3+1]=0.0f; acc_v[n*96+g*3+2]=0.0f;
    float os=0.f, o0=0.f, o1=0.f, o2=0.f;
    #pragma unroll
    for (int f=0;f<FF;f++){
        float a  = __shfl(asv, f, 32);
        float b0 = __shfl(av0, f, 32);
        float b1 = __shfl(av1, f, 32);
        float b2 = __shfl(av2, f, 32);
        float ws = Wsl[f*32+g];
        float wv = Wvl[f*32+g];
        os += a*ws; o0 += b0*wv; o1 += b1*wv; o2 += b2*wv;
    }
    ns[n*32+g] += elu_f(os);
    nv[n*96+g*3+0] += o0;
    nv[n*96+g*3+1] += o1;
    nv[n*96+g*3+2] += o2;
}

// ---------------- invariant map + graph pooling (atomics) ----------------
__global__ __launch_bounds__(256) void k_inv(
    const float* __restrict__ ns, const float* __restrict__ nv,
    const int* __restrict__ batch,
    const float* __restrict__ W_inv, const float* __restrict__ b_inv,
    float* __restrict__ xg_acc, float* __restrict__ gcnt)
{
    __shared__ float feat[2][64];
    int local = threadIdx.x >> 7;
    int j = threadIdx.x & 127;
    int n = blockIdx.x*2 + local;
    if (j < 32) {
        feat[local][j] = ns[n*32+j];
    } else if (j < 64) {
        int f = j-32;
        float v0=nv[n*96+f*3+0], v1=nv[n*96+f*3+1], v2=nv[n*96+f*3+2];
        feat[local][j] = sqrtf(v0*v0+v1*v1+v2*v2+EPSF);
    }
    __syncthreads();
    float a = b_inv[j];
    #pragma unroll
    for (int k=0;k<64;k++) a += feat[local][k]*W_inv[k*128+j];
    int b = batch[n];
    atomicAdd(&xg_acc[b*128+j], a);
    if (j==0) atomicAdd(&gcnt[b], 1.0f);
}

// ---------------- pooled mean ----------------
__global__ __launch_bounds__(256) void k_pool(
    const float* __restrict__ xg_acc, const float* __restrict__ gcnt, float* __restrict__ xg)
{
    int tid = blockIdx.x*256 + threadIdx.x;
    if (tid >= GG*128) return;
    int g = tid >> 7;
    xg[tid] = xg_acc[tid] / fmaxf(gcnt[g], 1.0f);
}

// ---------------- per-column mean/rstd over G rows ----------------
__global__ __launch_bounds__(256) void k_colstats(
    const float* __restrict__ in, float* __restrict__ mean, float* __restrict__ rstd)
{
    int j = blockIdx.x;
    float s=0.f, q=0.f;
    for (int g=threadIdx.x; g<GG; g+=256){
        float x = in[g*128+j];
        s += x; q += x*x;
    }
    __shared__ float rs[256], rq[256];
    rs[threadIdx.x]=s; rq[threadIdx.x]=q;
    __syncthreads();
    for (int st=128; st>0; st>>=1){
        if (threadIdx.x < st){ rs[threadIdx.x]+=rs[threadIdx.x+st]; rq[threadIdx.x]+=rq[threadIdx.x+st]; }
        __syncthreads();
    }
    if (threadIdx.x==0){
        float m = rs[0]/(float)GG;
        float v = rq[0]/(float)GG - m*m;
        mean[j]=m; rstd[j]=rsqrtf(v+1e-5f);
    }
}

// ---------------- BN1 + ELU + FC1 ----------------
__global__ __launch_bounds__(128) void k_fc1(
    const float* __restrict__ xg, const float* __restrict__ mean, const float* __restrict__ rstd,
    const float* __restrict__ g1, const float* __restrict__ be1,
    const float* __restrict__ Wf1, const float* __restrict__ bf1,
    float* __restrict__ z1)
{
    int g = blockIdx.x, j = threadIdx.x;
    __shared__ float a[128];
    float xin = xg[g*128+j];
    a[j] = elu_f((xin-mean[j])*rstd[j]*g1[j]+be1[j]);
    __syncthreads();
    float z = bf1[j];
    #pragma unroll 8
    for (int k=0;k<128;k++) z += a[k]*Wf1[k*128+j];
    z1[g*128+j] = z;
}

// ---------------- BN2 + ELU + FC2 -> out ----------------
__global__ __launch_bounds__(128) void k_out(
    const float* __restrict__ z1, const float* __restrict__ mean, const float* __restrict__ rstd,
    const float* __restrict__ g2, const float* __restrict__ be2,
    const float* __restrict__ Wf2, const float* __restrict__ bf2,
    float* __restrict__ out)
{
    int g = blockIdx.x, j = threadIdx.x;
    float a = elu_f((z1[g*128+j]-mean[j])*rstd[j]*g2[j]+be2[j]) * Wf2[j];
    __shared__ float red[128];
    red[j]=a; __syncthreads();
    for (int st=64; st>0; st>>=1){
        if (j<st) red[j]+=red[j+st];
        __syncthreads();
    }
    if (j==0) out[g] = red[0] + bf2[0];
}

extern "C" void kernel_launch(void* const* d_in, const int* in_sizes, int n_in,
                              void* d_out, int out_size, void* d_ws, size_t ws_size,
                              hipStream_t stream)
{
    const float* x      = (const float*)d_in[0];
    const float* pos    = (const float*)d_in[1];
    const int*   ei     = (const int*)d_in[2];
    const float* eattr  = (const float*)d_in[3];
    const int*   batch  = (const int*)d_in[4];
    const float* W_es   = (const float*)d_in[5];
    const float* b_es   = (const float*)d_in[6];
    const float* W_ev   = (const float*)d_in[7];
    const float* W1     = (const float*)d_in[8];
    const float* b1     = (const float*)d_in[9];
    const float* W2     = (const float*)d_in[10];
    const float* b2     = (const float*)d_in[11];
    const float* Ws     = (const float*)d_in[12];
    const float* Wv     = (const float*)d_in[13];
    const float* W_inv  = (const float*)d_in[14];
    const float* b_inv  = (const float*)d_in[15];
    const float* g1     = (const float*)d_in[16];
    const float* be1    = (const float*)d_in[17];
    const float* Wf1    = (const float*)d_in[18];
    const float* bf1    = (const float*)d_in[19];
    const float* g2     = (const float*)d_in[20];
    const float* be2    = (const float*)d_in[21];
    const float* Wf2    = (const float*)d_in[22];
    const float* bf2    = (const float*)d_in[23];
    float* out = (float*)d_out;

    // workspace layout (floats); zero-init region first
    float* ws      = (float*)d_ws;
    float* counts  = ws;                    // N
    float* acc_s   = counts + 50000;        // N*32
    float* acc_v   = acc_s + 1600000;       // N*96
    float* xg_acc  = acc_v + 4800000;       // G*128
    float* gcnt    = xg_acc + 262144;       // G
    const size_t zero_floats = 50000ULL + 1600000ULL + 4800000ULL + 262144ULL + 2048ULL;
    float* dedge   = ws + zero_floats;      // E
    float* uvec    = dedge + 800000;        // E*3
    float* ns      = uvec + 2400000;        // N*32
    float* nv      = ns + 1600000;          // N*96
    float* W2T     = nv + 4800000;          // NL*96*64
    float* xg      = W2T + 24576;           // G*128
    float* z1      = xg + 262144;           // G*128
    float* m1      = z1 + 262144;
    float* r1      = m1 + 128;
    float* m2      = r1 + 128;
    float* r2      = m2 + 128;

    hipMemsetAsync(d_ws, 0, zero_floats*sizeof(float), stream);

    k_transpose<<<(NLAYERS*6144+255)/256, 256, 0, stream>>>(W2, W2T);
    k_edgegeo<<<EE/256, 256, 0, stream>>>(ei, pos, dedge, uvec, counts);
    k_embed<<<NN*FF/256, 256, 0, stream>>>(x, pos, W_es, b_es, W_ev, ns, nv);

    for (int l=0; l<NLAYERS; l++){
        k_msg<<<EE/256, 256, 0, stream>>>(ei, dedge, uvec, eattr,
            W1 + l*320, b1 + l*64, W2T + l*6144, b2 + l*96,
            ns, nv, acc_s, acc_v);
        k_nodeupd<<<NN*32/256, 256, 0, stream>>>(counts, Ws + l*1024, Wv + l*1024,
            acc_s, acc_v, ns, nv);
    }

    k_inv<<<NN/2, 256, 0, stream>>>(ns, nv, batch, W_inv, b_inv, xg_acc, gcnt);
    k_pool<<<GG*128/256, 256, 0, stream>>>(xg_acc, gcnt, xg);
    k_colstats<<<128, 256, 0, stream>>>(xg, m1, r1);
    k_fc1<<<GG, 128, 0, stream>>>(xg, m1, r1, g1, be1, Wf1, bf1, z1);
    k_colstats<<<128, 256, 0, stream>>>(z1, m2, r2);
    k_out<<<GG, 128, 0, stream>>>(z1, m2, r2, g2, be2, Wf2, bf2, out);
}

// Round 2
// 5559.412 us; speedup vs baseline: 3.7687x; 3.7687x over previous
//
#include <hip/hip_runtime.h>
#include <hip/hip_bf16.h>
#include <math.h>

#define NN 50000
#define EE 800000
#define FF 32
#define HH 64
#define GG 2048
#define NLAYERS 4
#define EPSF 1e-6f

__device__ __forceinline__ float elu_f(float x){ return x > 0.0f ? x : __expf(x) - 1.0f; }

// ---------------- in-degree count ----------------
__global__ __launch_bounds__(256) void k_count(const int* __restrict__ ei, int* __restrict__ counts)
{
    int e = blockIdx.x*256 + threadIdx.x;
    if (e >= EE) return;
    atomicAdd(&counts[ei[EE+e]], 1);
}

// ---------------- exclusive scan over counts -> rowptr (single block) ----------------
__global__ __launch_bounds__(1024) void k_scan(const int* __restrict__ counts, int* __restrict__ rowptr)
{
    __shared__ int sh[1024];
    const int CH = (NN + 1023)/1024;  // 49
    int t = threadIdx.x;
    int start = t*CH;
    int end = min(start+CH, NN);
    int s = 0;
    for (int i=start; i<end; i++) s += counts[i];
    sh[t] = s; __syncthreads();
    for (int off=1; off<1024; off<<=1){
        int v = (t>=off) ? sh[t-off] : 0;
        __syncthreads();
        sh[t] += v;
        __syncthreads();
    }
    int run = sh[t] - s;   // exclusive prefix
    for (int i=start; i<end; i++){ rowptr[i] = run; run += counts[i]; }
    if (t==1023) rowptr[NN] = run;
}

// ---------------- CSR fill: geometry + edge inputs in dst-sorted order ----------------
__global__ __launch_bounds__(256) void k_fill(
    const int* __restrict__ ei, const float* __restrict__ pos, const float* __restrict__ eattr,
    const int* __restrict__ rowptr, int* __restrict__ cursor,
    int* __restrict__ esrc, float* __restrict__ ein8)
{
    int e = blockIdx.x*256 + threadIdx.x;
    if (e >= EE) return;
    int src = ei[e], dst = ei[EE+e];
    float dx = pos[dst*3+0]-pos[src*3+0];
    float dy = pos[dst*3+1]-pos[src*3+1];
    float dz = pos[dst*3+2]-pos[src*3+2];
    float d = sqrtf(dx*dx+dy*dy+dz*dz+EPSF);
    float inv = 1.0f/d;
    int slot = rowptr[dst] + atomicAdd(&cursor[dst], 1);
    esrc[slot] = src;
    float4* p = (float4*)(ein8 + (size_t)slot*8);
    p[0] = make_float4(d, eattr[e*4+0], eattr[e*4+1], eattr[e*4+2]);
    p[1] = make_float4(eattr[e*4+3], dx*inv, dy*inv, dz*inv);
}

// ---------------- node embedding ----------------
__global__ __launch_bounds__(256) void k_embed(
    const float* __restrict__ x, const float* __restrict__ pos,
    const float* __restrict__ W_es, const float* __restrict__ b_es,
    const float* __restrict__ W_ev,
    float* __restrict__ ns, float* __restrict__ nv)
{
    int tid = blockIdx.x*256 + threadIdx.x;
    if (tid >= NN*FF) return;
    int n = tid >> 5, f = tid & 31;
    float x0=x[n*5+0], x1=x[n*5+1], x2=x[n*5+2], x3=x[n*5+3], x4=x[n*5+4];
    float s  = b_es[f] + x0*W_es[f] + x1*W_es[32+f] + x2*W_es[64+f] + x3*W_es[96+f] + x4*W_es[128+f];
    float vm =           x0*W_ev[f] + x1*W_ev[32+f] + x2*W_ev[64+f] + x3*W_ev[96+f] + x4*W_ev[128+f];
    ns[tid] = s;
    nv[n*96+f*3+0] = vm*pos[n*3+0];
    nv[n*96+f*3+1] = vm*pos[n*3+1];
    nv[n*96+f*3+2] = vm*pos[n*3+2];
}

// ---------------- W2 transpose: [l][k(64)][j(96)] -> [l][j(96)][k(64)] ----------------
__global__ __launch_bounds__(256) void k_transpose(const float* __restrict__ W2, float* __restrict__ W2T)
{
    int tid = blockIdx.x*256 + threadIdx.x;
    if (tid >= NLAYERS*6144) return;
    int l = tid / 6144; int r = tid - l*6144;
    int j = r >> 6; int k = r & 63;
    W2T[l*6144 + j*64 + k] = W2[l*6144 + k*96 + j];
}

// ---------------- edge MLP -> bf16 h[slot][96] in CSR order ----------------
__global__ __launch_bounds__(256,4) void k_mlp(
    const float* __restrict__ ein8,
    const float* __restrict__ W1l, const float* __restrict__ b1l,
    const float* __restrict__ W2Tl, const float* __restrict__ b2l,
    __hip_bfloat16* __restrict__ hbuf)
{
    int slot = blockIdx.x*256 + threadIdx.x;
    if (slot >= EE) return;
    const float4* p = (const float4*)(ein8 + (size_t)slot*8);
    float4 q0 = p[0], q1 = p[1];
    float e0=q0.x, e1=q0.y, e2=q0.z, e3=q0.w, e4=q1.x;
    float hidden[HH];
    #pragma unroll
    for (int k=0;k<HH;k++){
        float a = b1l[k] + e0*W1l[k] + e1*W1l[64+k] + e2*W1l[128+k]
                         + e3*W1l[192+k] + e4*W1l[256+k];
        hidden[k] = elu_f(a);
    }
    __hip_bfloat16* hb = hbuf + (size_t)slot*96;
    for (int f=0; f<FF; f++){
        const float* c0 = W2Tl + f*64;
        const float* c1 = W2Tl + (f+32)*64;
        const float* c2 = W2Tl + (f+64)*64;
        float gs = b2l[f], gv = b2l[32+f], gsv = b2l[64+f];
        #pragma unroll
        for (int k=0;k<HH;k++){
            gs  += hidden[k]*c0[k];
            gv  += hidden[k]*c1[k];
            gsv += hidden[k]*c2[k];
        }
        hb[f]    = __float2bfloat16(gs);
        hb[32+f] = __float2bfloat16(gv);
        hb[64+f] = __float2bfloat16(gsv);
    }
}

// ---------------- CSR gather-aggregate + node update (no atomics) ----------------
__global__ __launch_bounds__(256) void k_agg(
    const int* __restrict__ rowptr, const int* __restrict__ esrc,
    const float* __restrict__ ein8, const __hip_bfloat16* __restrict__ hbuf,
    const float* __restrict__ nsi, const float* __restrict__ nvi,
    const float* __restrict__ Wsl, const float* __restrict__ Wvl,
    float* __restrict__ nso, float* __restrict__ nvo)
{
    int tid = blockIdx.x*256 + threadIdx.x;
    int n = tid >> 5, f = tid & 31;
    if (n >= NN) return;
    int beg = rowptr[n], end = rowptr[n+1];
    float as=0.f, a0=0.f, a1=0.f, a2=0.f;
    for (int slot=beg; slot<end; slot++){
        const __hip_bfloat16* hb = hbuf + (size_t)slot*96;
        float gs  = __bfloat162float(hb[f]);
        float gv  = __bfloat162float(hb[32+f]);
        float gsv = __bfloat162float(hb[64+f]);
        int src = esrc[slot];
        float u0 = ein8[slot*8+5], u1 = ein8[slot*8+6], u2 = ein8[slot*8+7];
        float s  = nsi[src*32+f];
        float v0 = nvi[src*96+f*3+0], v1 = nvi[src*96+f*3+1], v2 = nvi[src*96+f*3+2];
        float c = gsv*s;
        as += gs*s;
        a0 += gv*v0 + c*u0;
        a1 += gv*v1 + c*u1;
        a2 += gv*v2 + c*u2;
    }
    float inv = 1.f/fmaxf((float)(end-beg), 1.f);
    as*=inv; a0*=inv; a1*=inv; a2*=inv;
    float os=0.f, o0=0.f, o1=0.f, o2=0.f;
    #pragma unroll
    for (int k=0;k<FF;k++){
        float bs = __shfl(as, k, 32);
        float b0 = __shfl(a0, k, 32);
        float b1 = __shfl(a1, k, 32);
        float b2 = __shfl(a2, k, 32);
        float ws = Wsl[k*32+f];
        float wv = Wvl[k*32+f];
        os += bs*ws; o0 += b0*wv; o1 += b1*wv; o2 += b2*wv;
    }
    nso[n*32+f] = nsi[n*32+f] + elu_f(os);
    nvo[n*96+f*3+0] = nvi[n*96+f*3+0] + o0;
    nvo[n*96+f*3+1] = nvi[n*96+f*3+1] + o1;
    nvo[n*96+f*3+2] = nvi[n*96+f*3+2] + o2;
}

// ---------------- graph boundaries via binary search (batch is sorted) ----------------
__global__ __launch_bounds__(256) void k_gbounds(const int* __restrict__ batch, int* __restrict__ gstart)
{
    int g = blockIdx.x*256 + threadIdx.x;
    if (g > GG) return;
    int lo = 0, hi = NN;
    while (lo < hi){
        int mid = (lo+hi) >> 1;
        if (batch[mid] < g) lo = mid+1; else hi = mid;
    }
    gstart[g] = lo;
}

// ---------------- invariant map + graph mean pool (no atomics) ----------------
__global__ __launch_bounds__(128) void k_gpool(
    const int* __restrict__ gstart,
    const float* __restrict__ ns, const float* __restrict__ nv,
    const float* __restrict__ W_inv, const float* __restrict__ b_inv,
    float* __restrict__ xg)
{
    __shared__ float Wsh[64*128];
    __shared__ float feat[64];
    int g = blockIdx.x, j = threadIdx.x;
    for (int idx=j; idx<64*128; idx+=128) Wsh[idx] = W_inv[idx];
    int beg = gstart[g], end = gstart[g+1];
    float acc = 0.f;
    for (int n=beg; n<end; n++){
        __syncthreads();
        if (j < 32){
            feat[j] = ns[n*32+j];
        } else if (j < 64){
            int f = j-32;
            float v0=nv[n*96+f*3+0], v1=nv[n*96+f*3+1], v2=nv[n*96+f*3+2];
            feat[j] = sqrtf(v0*v0+v1*v1+v2*v2+EPSF);
        }
        __syncthreads();
        float a = 0.f;
        #pragma unroll
        for (int k=0;k<64;k++) a += feat[k]*Wsh[k*128+j];
        acc += a;
    }
    int cnt = end - beg;
    float cp = fmaxf((float)cnt, 1.f);
    xg[g*128+j] = acc/cp + b_inv[j]*((float)cnt/cp);
}

// ---------------- per-column mean/rstd over G rows ----------------
__global__ __launch_bounds__(256) void k_colstats(
    const float* __restrict__ in, float* __restrict__ mean, float* __restrict__ rstd)
{
    int j = blockIdx.x;
    float s=0.f, q=0.f;
    for (int g=threadIdx.x; g<GG; g+=256){
        float x = in[g*128+j];
        s += x; q += x*x;
    }
    __shared__ float rs[256], rq[256];
    rs[threadIdx.x]=s; rq[threadIdx.x]=q;
    __syncthreads();
    for (int st=128; st>0; st>>=1){
        if (threadIdx.x < st){ rs[threadIdx.x]+=rs[threadIdx.x+st]; rq[threadIdx.x]+=rq[threadIdx.x+st]; }
        __syncthreads();
    }
    if (threadIdx.x==0){
        float m = rs[0]/(float)GG;
        float v = rq[0]/(float)GG - m*m;
        mean[j]=m; rstd[j]=rsqrtf(v+1e-5f);
    }
}

// ---------------- BN1 + ELU + FC1 ----------------
__global__ __launch_bounds__(128) void k_fc1(
    const float* __restrict__ xg, const float* __restrict__ mean, const float* __restrict__ rstd,
    const float* __restrict__ g1, const float* __restrict__ be1,
    const float* __restrict__ Wf1, const float* __restrict__ bf1,
    float* __restrict__ z1)
{
    int g = blockIdx.x, j = threadIdx.x;
    __shared__ float a[128];
    float xin = xg[g*128+j];
    a[j] = elu_f((xin-mean[j])*rstd[j]*g1[j]+be1[j]);
    __syncthreads();
    float z = bf1[j];
    #pragma unroll 8
    for (int k=0;k<128;k++) z += a[k]*Wf1[k*128+j];
    z1[g*128+j] = z;
}

// ---------------- BN2 + ELU + FC2 -> out ----------------
__global__ __launch_bounds__(128) void k_out(
    const float* __restrict__ z1, const float* __restrict__ mean, const float* __restrict__ rstd,
    const float* __restrict__ g2, const float* __restrict__ be2,
    const float* __restrict__ Wf2, const float* __restrict__ bf2,
    float* __restrict__ out)
{
    int g = blockIdx.x, j = threadIdx.x;
    float a = elu_f((z1[g*128+j]-mean[j])*rstd[j]*g2[j]+be2[j]) * Wf2[j];
    __shared__ float red[128];
    red[j]=a; __syncthreads();
    for (int st=64; st>0; st>>=1){
        if (j<st) red[j]+=red[j+st];
        __syncthreads();
    }
    if (j==0) out[g] = red[0] + bf2[0];
}

extern "C" void kernel_launch(void* const* d_in, const int* in_sizes, int n_in,
                              void* d_out, int out_size, void* d_ws, size_t ws_size,
                              hipStream_t stream)
{
    const float* x      = (const float*)d_in[0];
    const float* pos    = (const float*)d_in[1];
    const int*   ei     = (const int*)d_in[2];
    const float* eattr  = (const float*)d_in[3];
    const int*   batch  = (const int*)d_in[4];
    const float* W_es   = (const float*)d_in[5];
    const float* b_es   = (const float*)d_in[6];
    const float* W_ev   = (const float*)d_in[7];
    const float* W1     = (const float*)d_in[8];
    const float* b1     = (const float*)d_in[9];
    const float* W2     = (const float*)d_in[10];
    const float* b2     = (const float*)d_in[11];
    const float* Ws     = (const float*)d_in[12];
    const float* Wv     = (const float*)d_in[13];
    const float* W_inv  = (const float*)d_in[14];
    const float* b_inv  = (const float*)d_in[15];
    const float* g1     = (const float*)d_in[16];
    const float* be1    = (const float*)d_in[17];
    const float* Wf1    = (const float*)d_in[18];
    const float* bf1    = (const float*)d_in[19];
    const float* g2     = (const float*)d_in[20];
    const float* be2    = (const float*)d_in[21];
    const float* Wf2    = (const float*)d_in[22];
    const float* bf2    = (const float*)d_in[23];
    float* out = (float*)d_out;

    // ---- workspace layout (4-byte units, 16-elt aligned blocks) ----
    char* base = (char*)d_ws;
    size_t off = 0;
    auto alloc = [&](size_t elems4) { // elems in 4-byte units
        void* p = base + off;
        off += ((elems4*4 + 63) & ~size_t(63));
        return p;
    };
    int*   counts = (int*)  alloc(50000);       // zeroed
    int*   cursor = (int*)  alloc(50000);       // zeroed
    size_t zero_bytes = off;
    int*   rowptr = (int*)  alloc(50001);
    int*   esrc   = (int*)  alloc(800000);
    float* ein8   = (float*)alloc(6400000);     // [E][8]: d,a0..a3,u0,u1,u2
    float* nsA    = (float*)alloc(1600000);
    float* nvA    = (float*)alloc(4800000);
    float* nsB    = (float*)alloc(1600000);
    float* nvB    = (float*)alloc(4800000);
    float* W2T    = (float*)alloc(24576);
    int*   gstart = (int*)  alloc(2049);
    float* xg     = (float*)alloc(262144);
    float* z1     = (float*)alloc(262144);
    float* m1     = (float*)alloc(128);
    float* r1     = (float*)alloc(128);
    float* m2     = (float*)alloc(128);
    float* r2     = (float*)alloc(128);
    __hip_bfloat16* hbuf = (__hip_bfloat16*)alloc(38400000); // E*96 bf16 = 153.6 MB

    hipMemsetAsync(d_ws, 0, zero_bytes, stream);

    // ---- setup: CSR build + embedding + weight transpose ----
    k_count    <<<EE/256, 256, 0, stream>>>(ei, counts);
    k_scan     <<<1, 1024, 0, stream>>>(counts, rowptr);
    k_fill     <<<EE/256, 256, 0, stream>>>(ei, pos, eattr, rowptr, cursor, esrc, ein8);
    k_embed    <<<NN*FF/256, 256, 0, stream>>>(x, pos, W_es, b_es, W_ev, nsA, nvA);
    k_transpose<<<(NLAYERS*6144+255)/256, 256, 0, stream>>>(W2, W2T);

    // ---- message-passing layers (double-buffered node features) ----
    for (int l=0; l<NLAYERS; l++){
        const float* nsi = (l&1) ? nsB : nsA;
        const float* nvi = (l&1) ? nvB : nvA;
        float* nso = (l&1) ? nsA : nsB;
        float* nvo = (l&1) ? nvA : nvB;
        k_mlp<<<EE/256, 256, 0, stream>>>(ein8,
            W1 + l*320, b1 + l*64, W2T + l*6144, b2 + l*96, hbuf);
        k_agg<<<(NN*32+255)/256, 256, 0, stream>>>(rowptr, esrc, ein8, hbuf,
            nsi, nvi, Ws + l*1024, Wv + l*1024, nso, nvo);
    }
    // after 4 layers output is in A buffers

    // ---- invariant map + pooling + head ----
    k_gbounds <<<(GG+1+255)/256, 256, 0, stream>>>(batch, gstart);
    k_gpool   <<<GG, 128, 0, stream>>>(gstart, nsA, nvA, W_inv, b_inv, xg);
    k_colstats<<<128, 256, 0, stream>>>(xg, m1, r1);
    k_fc1     <<<GG, 128, 0, stream>>>(xg, m1, r1, g1, be1, Wf1, bf1, z1);
    k_colstats<<<128, 256, 0, stream>>>(z1, m2, r2);
    k_out     <<<GG, 128, 0, stream>>>(z1, m2, r2, g2, be2, Wf2, bf2, out);
}

// Round 3
// 4711.477 us; speedup vs baseline: 4.4469x; 1.1800x over previous
//
#include <hip/hip_runtime.h>
#include <hip/hip_bf16.h>
#include <math.h>

#define NN 50000
#define EE 800000
#define FF 32
#define HH 64
#define GG 2048
#define NLAYERS 4
#define EPSF 1e-6f

__device__ __forceinline__ float elu_f(float x){ return x > 0.0f ? x : __expf(x) - 1.0f; }

// ---------------- in-degree count ----------------
__global__ __launch_bounds__(256) void k_count(const int* __restrict__ ei, int* __restrict__ counts)
{
    int e = blockIdx.x*256 + threadIdx.x;
    if (e >= EE) return;
    atomicAdd(&counts[ei[EE+e]], 1);
}

// ---------------- exclusive scan over counts -> rowptr (single block) ----------------
__global__ __launch_bounds__(1024) void k_scan(const int* __restrict__ counts, int* __restrict__ rowptr)
{
    __shared__ int sh[1024];
    const int CH = (NN + 1023)/1024;  // 49
    int t = threadIdx.x;
    int start = t*CH;
    int end = min(start+CH, NN);
    int s = 0;
    for (int i=start; i<end; i++) s += counts[i];
    sh[t] = s; __syncthreads();
    for (int off=1; off<1024; off<<=1){
        int v = (t>=off) ? sh[t-off] : 0;
        __syncthreads();
        sh[t] += v;
        __syncthreads();
    }
    int run = sh[t] - s;   // exclusive prefix
    for (int i=start; i<end; i++){ rowptr[i] = run; run += counts[i]; }
    if (t==1023) rowptr[NN] = run;
}

// ---------------- CSR fill: geometry + edge inputs in dst-sorted order ----------------
__global__ __launch_bounds__(256) void k_fill(
    const int* __restrict__ ei, const float* __restrict__ pos, const float* __restrict__ eattr,
    const int* __restrict__ rowptr, int* __restrict__ cursor,
    int* __restrict__ esrc, float* __restrict__ ein8)
{
    int e = blockIdx.x*256 + threadIdx.x;
    if (e >= EE) return;
    int src = ei[e], dst = ei[EE+e];
    float dx = pos[dst*3+0]-pos[src*3+0];
    float dy = pos[dst*3+1]-pos[src*3+1];
    float dz = pos[dst*3+2]-pos[src*3+2];
    float d = sqrtf(dx*dx+dy*dy+dz*dz+EPSF);
    float inv = 1.0f/d;
    int slot = rowptr[dst] + atomicAdd(&cursor[dst], 1);
    esrc[slot] = src;
    float4* p = (float4*)(ein8 + (size_t)slot*8);
    p[0] = make_float4(d, eattr[e*4+0], eattr[e*4+1], eattr[e*4+2]);
    p[1] = make_float4(eattr[e*4+3], dx*inv, dy*inv, dz*inv);
}

// ---------------- node embedding ----------------
__global__ __launch_bounds__(256) void k_embed(
    const float* __restrict__ x, const float* __restrict__ pos,
    const float* __restrict__ W_es, const float* __restrict__ b_es,
    const float* __restrict__ W_ev,
    float* __restrict__ ns, float* __restrict__ nv)
{
    int tid = blockIdx.x*256 + threadIdx.x;
    if (tid >= NN*FF) return;
    int n = tid >> 5, f = tid & 31;
    float x0=x[n*5+0], x1=x[n*5+1], x2=x[n*5+2], x3=x[n*5+3], x4=x[n*5+4];
    float s  = b_es[f] + x0*W_es[f] + x1*W_es[32+f] + x2*W_es[64+f] + x3*W_es[96+f] + x4*W_es[128+f];
    float vm =           x0*W_ev[f] + x1*W_ev[32+f] + x2*W_ev[64+f] + x3*W_ev[96+f] + x4*W_ev[128+f];
    ns[tid] = s;
    nv[n*96+f*3+0] = vm*pos[n*3+0];
    nv[n*96+f*3+1] = vm*pos[n*3+1];
    nv[n*96+f*3+2] = vm*pos[n*3+2];
}

// ---------------- W2 transpose: [l][k(64)][j(96)] -> [l][j(96)][k(64)] ----------------
__global__ __launch_bounds__(256) void k_transpose(const float* __restrict__ W2, float* __restrict__ W2T)
{
    int tid = blockIdx.x*256 + threadIdx.x;
    if (tid >= NLAYERS*6144) return;
    int l = tid / 6144; int r = tid - l*6144;
    int j = r >> 6; int k = r & 63;
    W2T[l*6144 + j*64 + k] = W2[l*6144 + k*96 + j];
}

// ---------------- edge MLP -> bf16 h planes [96][E] in CSR slot order ----------------
__global__ __launch_bounds__(256,4) void k_mlp(
    const float* __restrict__ ein8,
    const float* __restrict__ W1l, const float* __restrict__ b1l,
    const float* __restrict__ W2Tl, const float* __restrict__ b2l,
    __hip_bfloat16* __restrict__ hbuf)
{
    int slot = blockIdx.x*256 + threadIdx.x;
    if (slot >= EE) return;
    const float4* p = (const float4*)(ein8 + (size_t)slot*8);
    float4 q0 = p[0], q1 = p[1];
    float e0=q0.x, e1=q0.y, e2=q0.z, e3=q0.w, e4=q1.x;
    float hidden[HH];
    #pragma unroll
    for (int k=0;k<HH;k++){
        float a = b1l[k] + e0*W1l[k] + e1*W1l[64+k] + e2*W1l[128+k]
                         + e3*W1l[192+k] + e4*W1l[256+k];
        hidden[k] = elu_f(a);
    }
    for (int f=0; f<FF; f++){
        const float* c0 = W2Tl + f*64;
        const float* c1 = W2Tl + (f+32)*64;
        const float* c2 = W2Tl + (f+64)*64;
        float gs = b2l[f], gv = b2l[32+f], gsv = b2l[64+f];
        #pragma unroll
        for (int k=0;k<HH;k++){
            gs  += hidden[k]*c0[k];
            gv  += hidden[k]*c1[k];
            gsv += hidden[k]*c2[k];
        }
        // plane-major layout: coalesced 2B stores (64 lanes -> 128B line-contiguous)
        hbuf[(size_t)f*EE      + slot] = __float2bfloat16(gs);
        hbuf[(size_t)(32+f)*EE + slot] = __float2bfloat16(gv);
        hbuf[(size_t)(64+f)*EE + slot] = __float2bfloat16(gsv);
    }
}

// ---------------- CSR gather-aggregate + node update (no atomics) ----------------
__global__ __launch_bounds__(256) void k_agg(
    const int* __restrict__ rowptr, const int* __restrict__ esrc,
    const float* __restrict__ ein8, const __hip_bfloat16* __restrict__ hbuf,
    const float* __restrict__ nsi, const float* __restrict__ nvi,
    const float* __restrict__ Wsl, const float* __restrict__ Wvl,
    float* __restrict__ nso, float* __restrict__ nvo)
{
    int tid = blockIdx.x*256 + threadIdx.x;
    int n = tid >> 5, f = tid & 31;
    if (n >= NN) return;
    int beg = rowptr[n], end = rowptr[n+1];
    const __hip_bfloat16* hs  = hbuf + (size_t)f*EE;
    const __hip_bfloat16* hv  = hbuf + (size_t)(32+f)*EE;
    const __hip_bfloat16* hsv = hbuf + (size_t)(64+f)*EE;
    float as=0.f, a0=0.f, a1=0.f, a2=0.f;
    for (int slot=beg; slot<end; slot++){
        float gs  = __bfloat162float(hs[slot]);
        float gv  = __bfloat162float(hv[slot]);
        float gsv = __bfloat162float(hsv[slot]);
        int src = esrc[slot];
        float u0 = ein8[slot*8+5], u1 = ein8[slot*8+6], u2 = ein8[slot*8+7];
        float s  = nsi[src*32+f];
        float v0 = nvi[src*96+f*3+0], v1 = nvi[src*96+f*3+1], v2 = nvi[src*96+f*3+2];
        float c = gsv*s;
        as += gs*s;
        a0 += gv*v0 + c*u0;
        a1 += gv*v1 + c*u1;
        a2 += gv*v2 + c*u2;
    }
    float inv = 1.f/fmaxf((float)(end-beg), 1.f);
    as*=inv; a0*=inv; a1*=inv; a2*=inv;
    float os=0.f, o0=0.f, o1=0.f, o2=0.f;
    #pragma unroll
    for (int k=0;k<FF;k++){
        float bs = __shfl(as, k, 32);
        float b0 = __shfl(a0, k, 32);
        float b1 = __shfl(a1, k, 32);
        float b2 = __shfl(a2, k, 32);
        float ws = Wsl[k*32+f];
        float wv = Wvl[k*32+f];
        os += bs*ws; o0 += b0*wv; o1 += b1*wv; o2 += b2*wv;
    }
    nso[n*32+f] = nsi[n*32+f] + elu_f(os);
    nvo[n*96+f*3+0] = nvi[n*96+f*3+0] + o0;
    nvo[n*96+f*3+1] = nvi[n*96+f*3+1] + o1;
    nvo[n*96+f*3+2] = nvi[n*96+f*3+2] + o2;
}

// ---------------- graph boundaries via binary search (batch is sorted) ----------------
__global__ __launch_bounds__(256) void k_gbounds(const int* __restrict__ batch, int* __restrict__ gstart)
{
    int g = blockIdx.x*256 + threadIdx.x;
    if (g > GG) return;
    int lo = 0, hi = NN;
    while (lo < hi){
        int mid = (lo+hi) >> 1;
        if (batch[mid] < g) lo = mid+1; else hi = mid;
    }
    gstart[g] = lo;
}

// ---------------- invariant map + graph mean pool (no atomics) ----------------
__global__ __launch_bounds__(128) void k_gpool(
    const int* __restrict__ gstart,
    const float* __restrict__ ns, const float* __restrict__ nv,
    const float* __restrict__ W_inv, const float* __restrict__ b_inv,
    float* __restrict__ xg)
{
    __shared__ float Wsh[64*128];
    __shared__ float feat[64];
    int g = blockIdx.x, j = threadIdx.x;
    for (int idx=j; idx<64*128; idx+=128) Wsh[idx] = W_inv[idx];
    int beg = gstart[g], end = gstart[g+1];
    float acc = 0.f;
    for (int n=beg; n<end; n++){
        __syncthreads();
        if (j < 32){
            feat[j] = ns[n*32+j];
        } else if (j < 64){
            int f = j-32;
            float v0=nv[n*96+f*3+0], v1=nv[n*96+f*3+1], v2=nv[n*96+f*3+2];
            feat[j] = sqrtf(v0*v0+v1*v1+v2*v2+EPSF);
        }
        __syncthreads();
        float a = 0.f;
        #pragma unroll
        for (int k=0;k<64;k++) a += feat[k]*Wsh[k*128+j];
        acc += a;
    }
    int cnt = end - beg;
    float cp = fmaxf((float)cnt, 1.f);
    xg[g*128+j] = acc/cp + b_inv[j]*((float)cnt/cp);
}

// ---------------- per-column mean/rstd over G rows ----------------
__global__ __launch_bounds__(256) void k_colstats(
    const float* __restrict__ in, float* __restrict__ mean, float* __restrict__ rstd)
{
    int j = blockIdx.x;
    float s=0.f, q=0.f;
    for (int g=threadIdx.x; g<GG; g+=256){
        float x = in[g*128+j];
        s += x; q += x*x;
    }
    __shared__ float rs[256], rq[256];
    rs[threadIdx.x]=s; rq[threadIdx.x]=q;
    __syncthreads();
    for (int st=128; st>0; st>>=1){
        if (threadIdx.x < st){ rs[threadIdx.x]+=rs[threadIdx.x+st]; rq[threadIdx.x]+=rq[threadIdx.x+st]; }
        __syncthreads();
    }
    if (threadIdx.x==0){
        float m = rs[0]/(float)GG;
        float v = rq[0]/(float)GG - m*m;
        mean[j]=m; rstd[j]=rsqrtf(v+1e-5f);
    }
}

// ---------------- BN1 + ELU + FC1 ----------------
__global__ __launch_bounds__(128) void k_fc1(
    const float* __restrict__ xg, const float* __restrict__ mean, const float* __restrict__ rstd,
    const float* __restrict__ g1, const float* __restrict__ be1,
    const float* __restrict__ Wf1, const float* __restrict__ bf1,
    float* __restrict__ z1)
{
    int g = blockIdx.x, j = threadIdx.x;
    __shared__ float a[128];
    float xin = xg[g*128+j];
    a[j] = elu_f((xin-mean[j])*rstd[j]*g1[j]+be1[j]);
    __syncthreads();
    float z = bf1[j];
    #pragma unroll 8
    for (int k=0;k<128;k++) z += a[k]*Wf1[k*128+j];
    z1[g*128+j] = z;
}

// ---------------- BN2 + ELU + FC2 -> out ----------------
__global__ __launch_bounds__(128) void k_out(
    const float* __restrict__ z1, const float* __restrict__ mean, const float* __restrict__ rstd,
    const float* __restrict__ g2, const float* __restrict__ be2,
    const float* __restrict__ Wf2, const float* __restrict__ bf2,
    float* __restrict__ out)
{
    int g = blockIdx.x, j = threadIdx.x;
    float a = elu_f((z1[g*128+j]-mean[j])*rstd[j]*g2[j]+be2[j]) * Wf2[j];
    __shared__ float red[128];
    red[j]=a; __syncthreads();
    for (int st=64; st>0; st>>=1){
        if (j<st) red[j]+=red[j+st];
        __syncthreads();
    }
    if (j==0) out[g] = red[0] + bf2[0];
}

extern "C" void kernel_launch(void* const* d_in, const int* in_sizes, int n_in,
                              void* d_out, int out_size, void* d_ws, size_t ws_size,
                              hipStream_t stream)
{
    const float* x      = (const float*)d_in[0];
    const float* pos    = (const float*)d_in[1];
    const int*   ei     = (const int*)d_in[2];
    const float* eattr  = (const float*)d_in[3];
    const int*   batch  = (const int*)d_in[4];
    const float* W_es   = (const float*)d_in[5];
    const float* b_es   = (const float*)d_in[6];
    const float* W_ev   = (const float*)d_in[7];
    const float* W1     = (const float*)d_in[8];
    const float* b1     = (const float*)d_in[9];
    const float* W2     = (const float*)d_in[10];
    const float* b2     = (const float*)d_in[11];
    const float* Ws     = (const float*)d_in[12];
    const float* Wv     = (const float*)d_in[13];
    const float* W_inv  = (const float*)d_in[14];
    const float* b_inv  = (const float*)d_in[15];
    const float* g1     = (const float*)d_in[16];
    const float* be1    = (const float*)d_in[17];
    const float* Wf1    = (const float*)d_in[18];
    const float* bf1    = (const float*)d_in[19];
    const float* g2     = (const float*)d_in[20];
    const float* be2    = (const float*)d_in[21];
    const float* Wf2    = (const float*)d_in[22];
    const float* bf2    = (const float*)d_in[23];
    float* out = (float*)d_out;

    // ---- workspace layout (4-byte units, 64B aligned blocks) ----
    char* base = (char*)d_ws;
    size_t off = 0;
    auto alloc = [&](size_t elems4) { // elems in 4-byte units
        void* p = base + off;
        off += ((elems4*4 + 63) & ~size_t(63));
        return p;
    };
    int*   counts = (int*)  alloc(50000);       // zeroed
    int*   cursor = (int*)  alloc(50000);       // zeroed
    size_t zero_bytes = off;
    int*   rowptr = (int*)  alloc(50001);
    int*   esrc   = (int*)  alloc(800000);
    float* ein8   = (float*)alloc(6400000);     // [E][8]: d,a0..a3,u0,u1,u2
    float* nsA    = (float*)alloc(1600000);
    float* nvA    = (float*)alloc(4800000);
    float* nsB    = (float*)alloc(1600000);
    float* nvB    = (float*)alloc(4800000);
    float* W2T    = (float*)alloc(24576);
    int*   gstart = (int*)  alloc(2049);
    float* xg     = (float*)alloc(262144);
    float* z1     = (float*)alloc(262144);
    float* m1     = (float*)alloc(128);
    float* r1     = (float*)alloc(128);
    float* m2     = (float*)alloc(128);
    float* r2     = (float*)alloc(128);
    __hip_bfloat16* hbuf = (__hip_bfloat16*)alloc(38400000); // [96][E] bf16 planes = 153.6 MB

    hipMemsetAsync(d_ws, 0, zero_bytes, stream);

    // ---- setup: CSR build + embedding + weight transpose ----
    k_count    <<<EE/256, 256, 0, stream>>>(ei, counts);
    k_scan     <<<1, 1024, 0, stream>>>(counts, rowptr);
    k_fill     <<<EE/256, 256, 0, stream>>>(ei, pos, eattr, rowptr, cursor, esrc, ein8);
    k_embed    <<<NN*FF/256, 256, 0, stream>>>(x, pos, W_es, b_es, W_ev, nsA, nvA);
    k_transpose<<<(NLAYERS*6144+255)/256, 256, 0, stream>>>(W2, W2T);

    // ---- message-passing layers (double-buffered node features) ----
    for (int l=0; l<NLAYERS; l++){
        const float* nsi = (l&1) ? nsB : nsA;
        const float* nvi = (l&1) ? nvB : nvA;
        float* nso = (l&1) ? nsA : nsB;
        float* nvo = (l&1) ? nvA : nvB;
        k_mlp<<<EE/256, 256, 0, stream>>>(ein8,
            W1 + l*320, b1 + l*64, W2T + l*6144, b2 + l*96, hbuf);
        k_agg<<<(NN*32+255)/256, 256, 0, stream>>>(rowptr, esrc, ein8, hbuf,
            nsi, nvi, Ws + l*1024, Wv + l*1024, nso, nvo);
    }
    // after 4 layers output is in A buffers

    // ---- invariant map + pooling + head ----
    k_gbounds <<<(GG+1+255)/256, 256, 0, stream>>>(batch, gstart);
    k_gpool   <<<GG, 128, 0, stream>>>(gstart, nsA, nvA, W_inv, b_inv, xg);
    k_colstats<<<128, 256, 0, stream>>>(xg, m1, r1);
    k_fc1     <<<GG, 128, 0, stream>>>(xg, m1, r1, g1, be1, Wf1, bf1, z1);
    k_colstats<<<128, 256, 0, stream>>>(z1, m2, r2);
    k_out     <<<GG, 128, 0, stream>>>(z1, m2, r2, g2, be2, Wf2, bf2, out);
}

// Round 4
// 3850.162 us; speedup vs baseline: 5.4417x; 1.2237x over previous
//
#include <hip/hip_runtime.h>
#include <hip/hip_bf16.h>
#include <math.h>

#define NN 50000
#define EE 800000
#define FF 32
#define HH 64
#define GG 2048
#define NLAYERS 4
#define EPSF 1e-6f

__device__ __forceinline__ float elu_f(float x){ return x > 0.0f ? x : __expf(x) - 1.0f; }

// ---------------- in-degree count ----------------
__global__ __launch_bounds__(256) void k_count(const int* __restrict__ ei, int* __restrict__ counts)
{
    int e = blockIdx.x*256 + threadIdx.x;
    if (e >= EE) return;
    atomicAdd(&counts[ei[EE+e]], 1);
}

// ---------------- exclusive scan over counts -> rowptr (single block) ----------------
__global__ __launch_bounds__(1024) void k_scan(const int* __restrict__ counts, int* __restrict__ rowptr)
{
    __shared__ int sh[1024];
    const int CH = (NN + 1023)/1024;  // 49
    int t = threadIdx.x;
    int start = t*CH;
    int end = min(start+CH, NN);
    int s = 0;
    for (int i=start; i<end; i++) s += counts[i];
    sh[t] = s; __syncthreads();
    for (int off=1; off<1024; off<<=1){
        int v = (t>=off) ? sh[t-off] : 0;
        __syncthreads();
        sh[t] += v;
        __syncthreads();
    }
    int run = sh[t] - s;   // exclusive prefix
    for (int i=start; i<end; i++){ rowptr[i] = run; run += counts[i]; }
    if (t==1023) rowptr[NN] = run;
}

// ---------------- CSR fill: geometry + edge inputs in dst-sorted order ----------------
__global__ __launch_bounds__(256) void k_fill(
    const int* __restrict__ ei, const float* __restrict__ pos, const float* __restrict__ eattr,
    const int* __restrict__ rowptr, int* __restrict__ cursor,
    int* __restrict__ esrc, float* __restrict__ ein8)
{
    int e = blockIdx.x*256 + threadIdx.x;
    if (e >= EE) return;
    int src = ei[e], dst = ei[EE+e];
    float dx = pos[dst*3+0]-pos[src*3+0];
    float dy = pos[dst*3+1]-pos[src*3+1];
    float dz = pos[dst*3+2]-pos[src*3+2];
    float d = sqrtf(dx*dx+dy*dy+dz*dz+EPSF);
    float inv = 1.0f/d;
    int slot = rowptr[dst] + atomicAdd(&cursor[dst], 1);
    esrc[slot] = src;
    float4* p = (float4*)(ein8 + (size_t)slot*8);
    p[0] = make_float4(d, eattr[e*4+0], eattr[e*4+1], eattr[e*4+2]);
    p[1] = make_float4(eattr[e*4+3], dx*inv, dy*inv, dz*inv);
}

// ---------------- node embedding ----------------
__global__ __launch_bounds__(256) void k_embed(
    const float* __restrict__ x, const float* __restrict__ pos,
    const float* __restrict__ W_es, const float* __restrict__ b_es,
    const float* __restrict__ W_ev,
    float* __restrict__ ns, float* __restrict__ nv)
{
    int tid = blockIdx.x*256 + threadIdx.x;
    if (tid >= NN*FF) return;
    int n = tid >> 5, f = tid & 31;
    float x0=x[n*5+0], x1=x[n*5+1], x2=x[n*5+2], x3=x[n*5+3], x4=x[n*5+4];
    float s  = b_es[f] + x0*W_es[f] + x1*W_es[32+f] + x2*W_es[64+f] + x3*W_es[96+f] + x4*W_es[128+f];
    float vm =           x0*W_ev[f] + x1*W_ev[32+f] + x2*W_ev[64+f] + x3*W_ev[96+f] + x4*W_ev[128+f];
    ns[tid] = s;
    nv[n*96+f*3+0] = vm*pos[n*3+0];
    nv[n*96+f*3+1] = vm*pos[n*3+1];
    nv[n*96+f*3+2] = vm*pos[n*3+2];
}

// ---------------- W2 transpose: [l][k(64)][j(96)] -> [l][j(96)][k(64)] ----------------
__global__ __launch_bounds__(256) void k_transpose(const float* __restrict__ W2, float* __restrict__ W2T)
{
    int tid = blockIdx.x*256 + threadIdx.x;
    if (tid >= NLAYERS*6144) return;
    int l = tid / 6144; int r = tid - l*6144;
    int j = r >> 6; int k = r & 63;
    W2T[l*6144 + j*64 + k] = W2[l*6144 + k*96 + j];
}

// ---------------- edge MLP -> bf16 h planes [96][E] in CSR slot order ----------------
// launch_bounds(256,2): allow ~128-256 VGPRs so hidden[64] stays in registers
// (R3 evidence: (256,4) pinned VGPR_Count=64 -> hidden spilled to scratch,
//  1.2 GB FETCH / 0.6 GB WRITE of spill traffic)
__global__ __launch_bounds__(256,2) void k_mlp(
    const float* __restrict__ ein8,
    const float* __restrict__ W1l, const float* __restrict__ b1l,
    const float* __restrict__ W2Tl, const float* __restrict__ b2l,
    __hip_bfloat16* __restrict__ hbuf)
{
    int slot = blockIdx.x*256 + threadIdx.x;
    if (slot >= EE) return;
    const float4* p = (const float4*)(ein8 + (size_t)slot*8);
    float4 q0 = p[0], q1 = p[1];
    float e0=q0.x, e1=q0.y, e2=q0.z, e3=q0.w, e4=q1.x;
    float hidden[HH];
    #pragma unroll
    for (int k=0;k<HH;k++){
        float a = b1l[k] + e0*W1l[k] + e1*W1l[64+k] + e2*W1l[128+k]
                         + e3*W1l[192+k] + e4*W1l[256+k];
        hidden[k] = elu_f(a);
    }
    for (int f=0; f<FF; f++){
        const float* c0 = W2Tl + f*64;
        const float* c1 = W2Tl + (f+32)*64;
        const float* c2 = W2Tl + (f+64)*64;
        float gs = b2l[f], gv = b2l[32+f], gsv = b2l[64+f];
        #pragma unroll
        for (int k=0;k<HH;k++){
            gs  += hidden[k]*c0[k];
            gv  += hidden[k]*c1[k];
            gsv += hidden[k]*c2[k];
        }
        // plane-major layout: coalesced 2B stores (64 lanes -> 128B line-contiguous)
        hbuf[(size_t)f*EE      + slot] = __float2bfloat16(gs);
        hbuf[(size_t)(32+f)*EE + slot] = __float2bfloat16(gv);
        hbuf[(size_t)(64+f)*EE + slot] = __float2bfloat16(gsv);
    }
}

// ---------------- CSR gather-aggregate + node update (no atomics) ----------------
__global__ __launch_bounds__(256) void k_agg(
    const int* __restrict__ rowptr, const int* __restrict__ esrc,
    const float* __restrict__ ein8, const __hip_bfloat16* __restrict__ hbuf,
    const float* __restrict__ nsi, const float* __restrict__ nvi,
    const float* __restrict__ Wsl, const float* __restrict__ Wvl,
    float* __restrict__ nso, float* __restrict__ nvo)
{
    int tid = blockIdx.x*256 + threadIdx.x;
    int n = tid >> 5, f = tid & 31;
    if (n >= NN) return;
    int beg = rowptr[n], end = rowptr[n+1];
    const __hip_bfloat16* hs  = hbuf + (size_t)f*EE;
    const __hip_bfloat16* hv  = hbuf + (size_t)(32+f)*EE;
    const __hip_bfloat16* hsv = hbuf + (size_t)(64+f)*EE;
    float as=0.f, a0=0.f, a1=0.f, a2=0.f;
    for (int slot=beg; slot<end; slot++){
        float gs  = __bfloat162float(hs[slot]);
        float gv  = __bfloat162float(hv[slot]);
        float gsv = __bfloat162float(hsv[slot]);
        int src = esrc[slot];
        float u0 = ein8[slot*8+5], u1 = ein8[slot*8+6], u2 = ein8[slot*8+7];
        float s  = nsi[src*32+f];
        float v0 = nvi[src*96+f*3+0], v1 = nvi[src*96+f*3+1], v2 = nvi[src*96+f*3+2];
        float c = gsv*s;
        as += gs*s;
        a0 += gv*v0 + c*u0;
        a1 += gv*v1 + c*u1;
        a2 += gv*v2 + c*u2;
    }
    float inv = 1.f/fmaxf((float)(end-beg), 1.f);
    as*=inv; a0*=inv; a1*=inv; a2*=inv;
    float os=0.f, o0=0.f, o1=0.f, o2=0.f;
    #pragma unroll
    for (int k=0;k<FF;k++){
        float bs = __shfl(as, k, 32);
        float b0 = __shfl(a0, k, 32);
        float b1 = __shfl(a1, k, 32);
        float b2 = __shfl(a2, k, 32);
        float ws = Wsl[k*32+f];
        float wv = Wvl[k*32+f];
        os += bs*ws; o0 += b0*wv; o1 += b1*wv; o2 += b2*wv;
    }
    nso[n*32+f] = nsi[n*32+f] + elu_f(os);
    nvo[n*96+f*3+0] = nvi[n*96+f*3+0] + o0;
    nvo[n*96+f*3+1] = nvi[n*96+f*3+1] + o1;
    nvo[n*96+f*3+2] = nvi[n*96+f*3+2] + o2;
}

// ---------------- graph boundaries via binary search (batch is sorted) ----------------
__global__ __launch_bounds__(256) void k_gbounds(const int* __restrict__ batch, int* __restrict__ gstart)
{
    int g = blockIdx.x*256 + threadIdx.x;
    if (g > GG) return;
    int lo = 0, hi = NN;
    while (lo < hi){
        int mid = (lo+hi) >> 1;
        if (batch[mid] < g) lo = mid+1; else hi = mid;
    }
    gstart[g] = lo;
}

// ---------------- invariant map + graph mean pool (no atomics) ----------------
__global__ __launch_bounds__(128) void k_gpool(
    const int* __restrict__ gstart,
    const float* __restrict__ ns, const float* __restrict__ nv,
    const float* __restrict__ W_inv, const float* __restrict__ b_inv,
    float* __restrict__ xg)
{
    __shared__ float Wsh[64*128];
    __shared__ float feat[64];
    int g = blockIdx.x, j = threadIdx.x;
    for (int idx=j; idx<64*128; idx+=128) Wsh[idx] = W_inv[idx];
    int beg = gstart[g], end = gstart[g+1];
    float acc = 0.f;
    for (int n=beg; n<end; n++){
        __syncthreads();
        if (j < 32){
            feat[j] = ns[n*32+j];
        } else if (j < 64){
            int f = j-32;
            float v0=nv[n*96+f*3+0], v1=nv[n*96+f*3+1], v2=nv[n*96+f*3+2];
            feat[j] = sqrtf(v0*v0+v1*v1+v2*v2+EPSF);
        }
        __syncthreads();
        float a = 0.f;
        #pragma unroll
        for (int k=0;k<64;k++) a += feat[k]*Wsh[k*128+j];
        acc += a;
    }
    int cnt = end - beg;
    float cp = fmaxf((float)cnt, 1.f);
    xg[g*128+j] = acc/cp + b_inv[j]*((float)cnt/cp);
}

// ---------------- per-column mean/rstd over G rows ----------------
__global__ __launch_bounds__(256) void k_colstats(
    const float* __restrict__ in, float* __restrict__ mean, float* __restrict__ rstd)
{
    int j = blockIdx.x;
    float s=0.f, q=0.f;
    for (int g=threadIdx.x; g<GG; g+=256){
        float x = in[g*128+j];
        s += x; q += x*x;
    }
    __shared__ float rs[256], rq[256];
    rs[threadIdx.x]=s; rq[threadIdx.x]=q;
    __syncthreads();
    for (int st=128; st>0; st>>=1){
        if (threadIdx.x < st){ rs[threadIdx.x]+=rs[threadIdx.x+st]; rq[threadIdx.x]+=rq[threadIdx.x+st]; }
        __syncthreads();
    }
    if (threadIdx.x==0){
        float m = rs[0]/(float)GG;
        float v = rq[0]/(float)GG - m*m;
        mean[j]=m; rstd[j]=rsqrtf(v+1e-5f);
    }
}

// ---------------- BN1 + ELU + FC1 ----------------
__global__ __launch_bounds__(128) void k_fc1(
    const float* __restrict__ xg, const float* __restrict__ mean, const float* __restrict__ rstd,
    const float* __restrict__ g1, const float* __restrict__ be1,
    const float* __restrict__ Wf1, const float* __restrict__ bf1,
    float* __restrict__ z1)
{
    int g = blockIdx.x, j = threadIdx.x;
    __shared__ float a[128];
    float xin = xg[g*128+j];
    a[j] = elu_f((xin-mean[j])*rstd[j]*g1[j]+be1[j]);
    __syncthreads();
    float z = bf1[j];
    #pragma unroll 8
    for (int k=0;k<128;k++) z += a[k]*Wf1[k*128+j];
    z1[g*128+j] = z;
}

// ---------------- BN2 + ELU + FC2 -> out ----------------
__global__ __launch_bounds__(128) void k_out(
    const float* __restrict__ z1, const float* __restrict__ mean, const float* __restrict__ rstd,
    const float* __restrict__ g2, const float* __restrict__ be2,
    const float* __restrict__ Wf2, const float* __restrict__ bf2,
    float* __restrict__ out)
{
    int g = blockIdx.x, j = threadIdx.x;
    float a = elu_f((z1[g*128+j]-mean[j])*rstd[j]*g2[j]+be2[j]) * Wf2[j];
    __shared__ float red[128];
    red[j]=a; __syncthreads();
    for (int st=64; st>0; st>>=1){
        if (j<st) red[j]+=red[j+st];
        __syncthreads();
    }
    if (j==0) out[g] = red[0] + bf2[0];
}

extern "C" void kernel_launch(void* const* d_in, const int* in_sizes, int n_in,
                              void* d_out, int out_size, void* d_ws, size_t ws_size,
                              hipStream_t stream)
{
    const float* x      = (const float*)d_in[0];
    const float* pos    = (const float*)d_in[1];
    const int*   ei     = (const int*)d_in[2];
    const float* eattr  = (const float*)d_in[3];
    const int*   batch  = (const int*)d_in[4];
    const float* W_es   = (const float*)d_in[5];
    const float* b_es   = (const float*)d_in[6];
    const float* W_ev   = (const float*)d_in[7];
    const float* W1     = (const float*)d_in[8];
    const float* b1     = (const float*)d_in[9];
    const float* W2     = (const float*)d_in[10];
    const float* b2     = (const float*)d_in[11];
    const float* Ws     = (const float*)d_in[12];
    const float* Wv     = (const float*)d_in[13];
    const float* W_inv  = (const float*)d_in[14];
    const float* b_inv  = (const float*)d_in[15];
    const float* g1     = (const float*)d_in[16];
    const float* be1    = (const float*)d_in[17];
    const float* Wf1    = (const float*)d_in[18];
    const float* bf1    = (const float*)d_in[19];
    const float* g2     = (const float*)d_in[20];
    const float* be2    = (const float*)d_in[21];
    const float* Wf2    = (const float*)d_in[22];
    const float* bf2    = (const float*)d_in[23];
    float* out = (float*)d_out;

    // ---- workspace layout (4-byte units, 64B aligned blocks) ----
    char* base = (char*)d_ws;
    size_t off = 0;
    auto alloc = [&](size_t elems4) { // elems in 4-byte units
        void* p = base + off;
        off += ((elems4*4 + 63) & ~size_t(63));
        return p;
    };
    int*   counts = (int*)  alloc(50000);       // zeroed
    int*   cursor = (int*)  alloc(50000);       // zeroed
    size_t zero_bytes = off;
    int*   rowptr = (int*)  alloc(50001);
    int*   esrc   = (int*)  alloc(800000);
    float* ein8   = (float*)alloc(6400000);     // [E][8]: d,a0..a3,u0,u1,u2
    float* nsA    = (float*)alloc(1600000);
    float* nvA    = (float*)alloc(4800000);
    float* nsB    = (float*)alloc(1600000);
    float* nvB    = (float*)alloc(4800000);
    float* W2T    = (float*)alloc(24576);
    int*   gstart = (int*)  alloc(2049);
    float* xg     = (float*)alloc(262144);
    float* z1     = (float*)alloc(262144);
    float* m1     = (float*)alloc(128);
    float* r1     = (float*)alloc(128);
    float* m2     = (float*)alloc(128);
    float* r2     = (float*)alloc(128);
    __hip_bfloat16* hbuf = (__hip_bfloat16*)alloc(38400000); // [96][E] bf16 planes = 153.6 MB

    hipMemsetAsync(d_ws, 0, zero_bytes, stream);

    // ---- setup: CSR build + embedding + weight transpose ----
    k_count    <<<EE/256, 256, 0, stream>>>(ei, counts);
    k_scan     <<<1, 1024, 0, stream>>>(counts, rowptr);
    k_fill     <<<EE/256, 256, 0, stream>>>(ei, pos, eattr, rowptr, cursor, esrc, ein8);
    k_embed    <<<NN*FF/256, 256, 0, stream>>>(x, pos, W_es, b_es, W_ev, nsA, nvA);
    k_transpose<<<(NLAYERS*6144+255)/256, 256, 0, stream>>>(W2, W2T);

    // ---- message-passing layers (double-buffered node features) ----
    for (int l=0; l<NLAYERS; l++){
        const float* nsi = (l&1) ? nsB : nsA;
        const float* nvi = (l&1) ? nvB : nvA;
        float* nso = (l&1) ? nsA : nsB;
        float* nvo = (l&1) ? nvA : nvB;
        k_mlp<<<EE/256, 256, 0, stream>>>(ein8,
            W1 + l*320, b1 + l*64, W2T + l*6144, b2 + l*96, hbuf);
        k_agg<<<(NN*32+255)/256, 256, 0, stream>>>(rowptr, esrc, ein8, hbuf,
            nsi, nvi, Ws + l*1024, Wv + l*1024, nso, nvo);
    }
    // after 4 layers output is in A buffers

    // ---- invariant map + pooling + head ----
    k_gbounds <<<(GG+1+255)/256, 256, 0, stream>>>(batch, gstart);
    k_gpool   <<<GG, 128, 0, stream>>>(gstart, nsA, nvA, W_inv, b_inv, xg);
    k_colstats<<<128, 256, 0, stream>>>(xg, m1, r1);
    k_fc1     <<<GG, 128, 0, stream>>>(xg, m1, r1, g1, be1, Wf1, bf1, z1);
    k_colstats<<<128, 256, 0, stream>>>(z1, m2, r2);
    k_out     <<<GG, 128, 0, stream>>>(z1, m2, r2, g2, be2, Wf2, bf2, out);
}

// Round 5
// 2436.418 us; speedup vs baseline: 8.5993x; 1.5803x over previous
//
#include <hip/hip_runtime.h>
#include <hip/hip_bf16.h>
#include <math.h>

#define NN 50000
#define EE 800000
#define FF 32
#define HH 64
#define GG 2048
#define NLAYERS 4
#define EPSF 1e-6f

typedef __attribute__((ext_vector_type(8))) short short8;
typedef __attribute__((ext_vector_type(4))) float f32x4;

__device__ __forceinline__ float elu_f(float x){ return x > 0.0f ? x : __expf(x) - 1.0f; }
__device__ __forceinline__ short f2bf_s(float x){
    __hip_bfloat16 h = __float2bfloat16(x);
    return *reinterpret_cast<short*>(&h);
}

// ---------------- in-degree count ----------------
__global__ __launch_bounds__(256) void k_count(const int* __restrict__ ei, int* __restrict__ counts)
{
    int e = blockIdx.x*256 + threadIdx.x;
    if (e >= EE) return;
    atomicAdd(&counts[ei[EE+e]], 1);
}

// ---------------- exclusive scan over counts -> rowptr (single block) ----------------
__global__ __launch_bounds__(1024) void k_scan(const int* __restrict__ counts, int* __restrict__ rowptr)
{
    __shared__ int sh[1024];
    const int CH = (NN + 1023)/1024;  // 49
    int t = threadIdx.x;
    int start = t*CH;
    int end = min(start+CH, NN);
    int s = 0;
    for (int i=start; i<end; i++) s += counts[i];
    sh[t] = s; __syncthreads();
    for (int off=1; off<1024; off<<=1){
        int v = (t>=off) ? sh[t-off] : 0;
        __syncthreads();
        sh[t] += v;
        __syncthreads();
    }
    int run = sh[t] - s;   // exclusive prefix
    for (int i=start; i<end; i++){ rowptr[i] = run; run += counts[i]; }
    if (t==1023) rowptr[NN] = run;
}

// ---------------- CSR fill: geometry + edge inputs in dst-sorted order ----------------
__global__ __launch_bounds__(256) void k_fill(
    const int* __restrict__ ei, const float* __restrict__ pos, const float* __restrict__ eattr,
    const int* __restrict__ rowptr, int* __restrict__ cursor,
    int* __restrict__ esrc, float* __restrict__ ein8)
{
    int e = blockIdx.x*256 + threadIdx.x;
    if (e >= EE) return;
    int src = ei[e], dst = ei[EE+e];
    float dx = pos[dst*3+0]-pos[src*3+0];
    float dy = pos[dst*3+1]-pos[src*3+1];
    float dz = pos[dst*3+2]-pos[src*3+2];
    float d = sqrtf(dx*dx+dy*dy+dz*dz+EPSF);
    float inv = 1.0f/d;
    int slot = rowptr[dst] + atomicAdd(&cursor[dst], 1);
    esrc[slot] = src;
    float4* p = (float4*)(ein8 + (size_t)slot*8);
    p[0] = make_float4(d, eattr[e*4+0], eattr[e*4+1], eattr[e*4+2]);
    p[1] = make_float4(eattr[e*4+3], dx*inv, dy*inv, dz*inv);
}

// ---------------- node embedding ----------------
__global__ __launch_bounds__(256) void k_embed(
    const float* __restrict__ x, const float* __restrict__ pos,
    const float* __restrict__ W_es, const float* __restrict__ b_es,
    const float* __restrict__ W_ev,
    float* __restrict__ ns, float* __restrict__ nv)
{
    int tid = blockIdx.x*256 + threadIdx.x;
    if (tid >= NN*FF) return;
    int n = tid >> 5, f = tid & 31;
    float x0=x[n*5+0], x1=x[n*5+1], x2=x[n*5+2], x3=x[n*5+3], x4=x[n*5+4];
    float s  = b_es[f] + x0*W_es[f] + x1*W_es[32+f] + x2*W_es[64+f] + x3*W_es[96+f] + x4*W_es[128+f];
    float vm =           x0*W_ev[f] + x1*W_ev[32+f] + x2*W_ev[64+f] + x3*W_ev[96+f] + x4*W_ev[128+f];
    ns[tid] = s;
    nv[n*96+f*3+0] = vm*pos[n*3+0];
    nv[n*96+f*3+1] = vm*pos[n*3+1];
    nv[n*96+f*3+2] = vm*pos[n*3+2];
}

// ---------------- W2 transpose -> bf16: [l][k(64)][j(96)] -> [l][j(96)][k(64)] ----------------
// bf16, k-contiguous: exactly the MFMA B-fragment layout (B^T[n][k])
__global__ __launch_bounds__(256) void k_transpose(const float* __restrict__ W2, __hip_bfloat16* __restrict__ W2bf)
{
    int tid = blockIdx.x*256 + threadIdx.x;
    if (tid >= NLAYERS*6144) return;
    int l = tid / 6144; int r = tid - l*6144;
    int j = r >> 6; int k = r & 63;
    W2bf[l*6144 + j*64 + k] = __float2bfloat16(W2[l*6144 + k*96 + j]);
}

// ---------------- edge MLP via MFMA -> bf16 h planes [96][E] ----------------
// Block = 256 thr = 4 waves, 16 edges/wave (64 edges/block).
// Lane l computes hidden[k] for edge (l&15), k = s*32 + (l>>4)*8 + j  == A-frag layout.
// B-frags read directly from global W2bf (L2-resident). 12 MFMAs/wave replace 6144 FMAs.
// C staged through LDS so hbuf planes get fully-coalesced 128B runs.
__global__ __launch_bounds__(256) void k_mlp_mfma(
    const float* __restrict__ ein8,
    const float* __restrict__ W1l, const float* __restrict__ b1l,
    const __hip_bfloat16* __restrict__ W2bfl, const float* __restrict__ b2l,
    __hip_bfloat16* __restrict__ hbuf)
{
    __shared__ __hip_bfloat16 cstage[96][72];   // 72 = 64 + 8 pad (row stride 144B, 16B-aligned)
    const int tid  = threadIdx.x;
    const int lane = tid & 63;
    const int wave = tid >> 6;
    const int m    = lane & 15;
    const int quad = lane >> 4;
    const long long blockbase = (long long)blockIdx.x * 64;
    const long long edge = blockbase + wave*16 + m;

    const float4* p = (const float4*)(ein8 + edge*8);
    float4 q0 = p[0], q1 = p[1];
    float e0=q0.x, e1=q0.y, e2=q0.z, e3=q0.w, e4=q1.x;

    // layer-1 straight into A-fragments
    short8 afrag[2];
    #pragma unroll
    for (int s=0;s<2;s++){
        #pragma unroll
        for (int j=0;j<8;j++){
            int k = s*32 + quad*8 + j;
            float a = b1l[k] + e0*W1l[k] + e1*W1l[64+k] + e2*W1l[128+k]
                             + e3*W1l[192+k] + e4*W1l[256+k];
            afrag[s][j] = f2bf_s(elu_f(a));
        }
    }

    f32x4 acc[6];
    #pragma unroll
    for (int t=0;t<6;t++) acc[t] = (f32x4){0.f,0.f,0.f,0.f};

    #pragma unroll
    for (int s=0;s<2;s++){
        #pragma unroll
        for (int t=0;t<6;t++){
            int n = t*16 + m;
            short8 bfrag = *(const short8*)(W2bfl + n*64 + s*32 + quad*8);
            acc[t] = __builtin_amdgcn_mfma_f32_16x16x32_bf16(afrag[s], bfrag, acc[t], 0, 0, 0);
        }
    }

    // C layout: row(edge-in-tile)=quad*4+reg, col(n-in-tile)=lane&15
    #pragma unroll
    for (int t=0;t<6;t++){
        int n = t*16 + m;
        float bias = b2l[n];
        #pragma unroll
        for (int r=0;r<4;r++){
            cstage[n][wave*16 + quad*4 + r] = __float2bfloat16(acc[t][r] + bias);
        }
    }
    __syncthreads();

    // cooperative coalesced store: 96 planes x 128B per block
    #pragma unroll
    for (int i=0;i<3;i++){
        int pl = i*32 + (tid>>3);
        int c  = tid & 7;
        float4 val = *(const float4*)&cstage[pl][c*8];
        *(float4*)(hbuf + (size_t)pl*EE + blockbase + c*8) = val;
    }
}

// ---------------- CSR gather-aggregate + node update (no atomics) ----------------
__global__ __launch_bounds__(256) void k_agg(
    const int* __restrict__ rowptr, const int* __restrict__ esrc,
    const float* __restrict__ ein8, const __hip_bfloat16* __restrict__ hbuf,
    const float* __restrict__ nsi, const float* __restrict__ nvi,
    const float* __restrict__ Wsl, const float* __restrict__ Wvl,
    float* __restrict__ nso, float* __restrict__ nvo)
{
    int tid = blockIdx.x*256 + threadIdx.x;
    int n = tid >> 5, f = tid & 31;
    if (n >= NN) return;
    int beg = rowptr[n], end = rowptr[n+1];
    const __hip_bfloat16* hs  = hbuf + (size_t)f*EE;
    const __hip_bfloat16* hv  = hbuf + (size_t)(32+f)*EE;
    const __hip_bfloat16* hsv = hbuf + (size_t)(64+f)*EE;
    float as=0.f, a0=0.f, a1=0.f, a2=0.f;
    for (int slot=beg; slot<end; slot++){
        float gs  = __bfloat162float(hs[slot]);
        float gv  = __bfloat162float(hv[slot]);
        float gsv = __bfloat162float(hsv[slot]);
        int src = esrc[slot];
        float u0 = ein8[slot*8+5], u1 = ein8[slot*8+6], u2 = ein8[slot*8+7];
        float s  = nsi[src*32+f];
        float v0 = nvi[src*96+f*3+0], v1 = nvi[src*96+f*3+1], v2 = nvi[src*96+f*3+2];
        float c = gsv*s;
        as += gs*s;
        a0 += gv*v0 + c*u0;
        a1 += gv*v1 + c*u1;
        a2 += gv*v2 + c*u2;
    }
    float inv = 1.f/fmaxf((float)(end-beg), 1.f);
    as*=inv; a0*=inv; a1*=inv; a2*=inv;
    float os=0.f, o0=0.f, o1=0.f, o2=0.f;
    #pragma unroll
    for (int k=0;k<FF;k++){
        float bs = __shfl(as, k, 32);
        float b0 = __shfl(a0, k, 32);
        float b1 = __shfl(a1, k, 32);
        float b2 = __shfl(a2, k, 32);
        float ws = Wsl[k*32+f];
        float wv = Wvl[k*32+f];
        os += bs*ws; o0 += b0*wv; o1 += b1*wv; o2 += b2*wv;
    }
    nso[n*32+f] = nsi[n*32+f] + elu_f(os);
    nvo[n*96+f*3+0] = nvi[n*96+f*3+0] + o0;
    nvo[n*96+f*3+1] = nvi[n*96+f*3+1] + o1;
    nvo[n*96+f*3+2] = nvi[n*96+f*3+2] + o2;
}

// ---------------- graph boundaries via binary search (batch is sorted) ----------------
__global__ __launch_bounds__(256) void k_gbounds(const int* __restrict__ batch, int* __restrict__ gstart)
{
    int g = blockIdx.x*256 + threadIdx.x;
    if (g > GG) return;
    int lo = 0, hi = NN;
    while (lo < hi){
        int mid = (lo+hi) >> 1;
        if (batch[mid] < g) lo = mid+1; else hi = mid;
    }
    gstart[g] = lo;
}

// ---------------- invariant map + graph mean pool (no atomics) ----------------
__global__ __launch_bounds__(128) void k_gpool(
    const int* __restrict__ gstart,
    const float* __restrict__ ns, const float* __restrict__ nv,
    const float* __restrict__ W_inv, const float* __restrict__ b_inv,
    float* __restrict__ xg)
{
    __shared__ float Wsh[64*128];
    __shared__ float feat[64];
    int g = blockIdx.x, j = threadIdx.x;
    for (int idx=j; idx<64*128; idx+=128) Wsh[idx] = W_inv[idx];
    int beg = gstart[g], end = gstart[g+1];
    float acc = 0.f;
    for (int n=beg; n<end; n++){
        __syncthreads();
        if (j < 32){
            feat[j] = ns[n*32+j];
        } else if (j < 64){
            int f = j-32;
            float v0=nv[n*96+f*3+0], v1=nv[n*96+f*3+1], v2=nv[n*96+f*3+2];
            feat[j] = sqrtf(v0*v0+v1*v1+v2*v2+EPSF);
        }
        __syncthreads();
        float a = 0.f;
        #pragma unroll
        for (int k=0;k<64;k++) a += feat[k]*Wsh[k*128+j];
        acc += a;
    }
    int cnt = end - beg;
    float cp = fmaxf((float)cnt, 1.f);
    xg[g*128+j] = acc/cp + b_inv[j]*((float)cnt/cp);
}

// ---------------- per-column mean/rstd over G rows ----------------
__global__ __launch_bounds__(256) void k_colstats(
    const float* __restrict__ in, float* __restrict__ mean, float* __restrict__ rstd)
{
    int j = blockIdx.x;
    float s=0.f, q=0.f;
    for (int g=threadIdx.x; g<GG; g+=256){
        float x = in[g*128+j];
        s += x; q += x*x;
    }
    __shared__ float rs[256], rq[256];
    rs[threadIdx.x]=s; rq[threadIdx.x]=q;
    __syncthreads();
    for (int st=128; st>0; st>>=1){
        if (threadIdx.x < st){ rs[threadIdx.x]+=rs[threadIdx.x+st]; rq[threadIdx.x]+=rq[threadIdx.x+st]; }
        __syncthreads();
    }
    if (threadIdx.x==0){
        float m = rs[0]/(float)GG;
        float v = rq[0]/(float)GG - m*m;
        mean[j]=m; rstd[j]=rsqrtf(v+1e-5f);
    }
}

// ---------------- BN1 + ELU + FC1 ----------------
__global__ __launch_bounds__(128) void k_fc1(
    const float* __restrict__ xg, const float* __restrict__ mean, const float* __restrict__ rstd,
    const float* __restrict__ g1, const float* __restrict__ be1,
    const float* __restrict__ Wf1, const float* __restrict__ bf1,
    float* __restrict__ z1)
{
    int g = blockIdx.x, j = threadIdx.x;
    __shared__ float a[128];
    float xin = xg[g*128+j];
    a[j] = elu_f((xin-mean[j])*rstd[j]*g1[j]+be1[j]);
    __syncthreads();
    float z = bf1[j];
    #pragma unroll 8
    for (int k=0;k<128;k++) z += a[k]*Wf1[k*128+j];
    z1[g*128+j] = z;
}

// ---------------- BN2 + ELU + FC2 -> out ----------------
__global__ __launch_bounds__(128) void k_out(
    const float* __restrict__ z1, const float* __restrict__ mean, const float* __restrict__ rstd,
    const float* __restrict__ g2, const float* __restrict__ be2,
    const float* __restrict__ Wf2, const float* __restrict__ bf2,
    float* __restrict__ out)
{
    int g = blockIdx.x, j = threadIdx.x;
    float a = elu_f((z1[g*128+j]-mean[j])*rstd[j]*g2[j]+be2[j]) * Wf2[j];
    __shared__ float red[128];
    red[j]=a; __syncthreads();
    for (int st=64; st>0; st>>=1){
        if (j<st) red[j]+=red[j+st];
        __syncthreads();
    }
    if (j==0) out[g] = red[0] + bf2[0];
}

extern "C" void kernel_launch(void* const* d_in, const int* in_sizes, int n_in,
                              void* d_out, int out_size, void* d_ws, size_t ws_size,
                              hipStream_t stream)
{
    const float* x      = (const float*)d_in[0];
    const float* pos    = (const float*)d_in[1];
    const int*   ei     = (const int*)d_in[2];
    const float* eattr  = (const float*)d_in[3];
    const int*   batch  = (const int*)d_in[4];
    const float* W_es   = (const float*)d_in[5];
    const float* b_es   = (const float*)d_in[6];
    const float* W_ev   = (const float*)d_in[7];
    const float* W1     = (const float*)d_in[8];
    const float* b1     = (const float*)d_in[9];
    const float* W2     = (const float*)d_in[10];
    const float* b2     = (const float*)d_in[11];
    const float* Ws     = (const float*)d_in[12];
    const float* Wv     = (const float*)d_in[13];
    const float* W_inv  = (const float*)d_in[14];
    const float* b_inv  = (const float*)d_in[15];
    const float* g1     = (const float*)d_in[16];
    const float* be1    = (const float*)d_in[17];
    const float* Wf1    = (const float*)d_in[18];
    const float* bf1    = (const float*)d_in[19];
    const float* g2     = (const float*)d_in[20];
    const float* be2    = (const float*)d_in[21];
    const float* Wf2    = (const float*)d_in[22];
    const float* bf2    = (const float*)d_in[23];
    float* out = (float*)d_out;

    // ---- workspace layout (4-byte units, 64B aligned blocks) ----
    char* base = (char*)d_ws;
    size_t off = 0;
    auto alloc = [&](size_t elems4) { // elems in 4-byte units
        void* p = base + off;
        off += ((elems4*4 + 63) & ~size_t(63));
        return p;
    };
    int*   counts = (int*)  alloc(50000);       // zeroed
    int*   cursor = (int*)  alloc(50000);       // zeroed
    size_t zero_bytes = off;
    int*   rowptr = (int*)  alloc(50001);
    int*   esrc   = (int*)  alloc(800000);
    float* ein8   = (float*)alloc(6400000);     // [E][8]: d,a0..a3,u0,u1,u2
    float* nsA    = (float*)alloc(1600000);
    float* nvA    = (float*)alloc(4800000);
    float* nsB    = (float*)alloc(1600000);
    float* nvB    = (float*)alloc(4800000);
    __hip_bfloat16* W2bf = (__hip_bfloat16*)alloc(12288); // NL*96*64 bf16
    int*   gstart = (int*)  alloc(2049);
    float* xg     = (float*)alloc(262144);
    float* z1     = (float*)alloc(262144);
    float* m1     = (float*)alloc(128);
    float* r1     = (float*)alloc(128);
    float* m2     = (float*)alloc(128);
    float* r2     = (float*)alloc(128);
    __hip_bfloat16* hbuf = (__hip_bfloat16*)alloc(38400000); // [96][E] bf16 planes = 153.6 MB

    hipMemsetAsync(d_ws, 0, zero_bytes, stream);

    // ---- setup: CSR build + embedding + weight transpose ----
    k_count    <<<EE/256, 256, 0, stream>>>(ei, counts);
    k_scan     <<<1, 1024, 0, stream>>>(counts, rowptr);
    k_fill     <<<EE/256, 256, 0, stream>>>(ei, pos, eattr, rowptr, cursor, esrc, ein8);
    k_embed    <<<NN*FF/256, 256, 0, stream>>>(x, pos, W_es, b_es, W_ev, nsA, nvA);
    k_transpose<<<(NLAYERS*6144+255)/256, 256, 0, stream>>>(W2, W2bf);

    // ---- message-passing layers (double-buffered node features) ----
    for (int l=0; l<NLAYERS; l++){
        const float* nsi = (l&1) ? nsB : nsA;
        const float* nvi = (l&1) ? nvB : nvA;
        float* nso = (l&1) ? nsA : nsB;
        float* nvo = (l&1) ? nvA : nvB;
        k_mlp_mfma<<<EE/64, 256, 0, stream>>>(ein8,
            W1 + l*320, b1 + l*64, W2bf + l*6144, b2 + l*96, hbuf);
        k_agg<<<(NN*32+255)/256, 256, 0, stream>>>(rowptr, esrc, ein8, hbuf,
            nsi, nvi, Ws + l*1024, Wv + l*1024, nso, nvo);
    }
    // after 4 layers output is in A buffers

    // ---- invariant map + pooling + head ----
    k_gbounds <<<(GG+1+255)/256, 256, 0, stream>>>(batch, gstart);
    k_gpool   <<<GG, 128, 0, stream>>>(gstart, nsA, nvA, W_inv, b_inv, xg);
    k_colstats<<<128, 256, 0, stream>>>(xg, m1, r1);
    k_fc1     <<<GG, 128, 0, stream>>>(xg, m1, r1, g1, be1, Wf1, bf1, z1);
    k_colstats<<<128, 256, 0, stream>>>(z1, m2, r2);
    k_out     <<<GG, 128, 0, stream>>>(z1, m2, r2, g2, be2, Wf2, bf2, out);
}

// Round 6
// 1208.159 us; speedup vs baseline: 17.3417x; 2.0166x over previous
//
#include <hip/hip_runtime.h>
#include <hip/hip_bf16.h>
#include <math.h>

#define NN 50000
#define EE 800000
#define FF 32
#define HH 64
#define GG 2048
#define NLAYERS 4
#define EPSF 1e-6f

typedef __attribute__((ext_vector_type(8))) short short8;
typedef __attribute__((ext_vector_type(4))) float f32x4;

__device__ __forceinline__ float elu_f(float x){ return x > 0.0f ? x : __expf(x) - 1.0f; }
__device__ __forceinline__ short f2bf_s(float x){
    __hip_bfloat16 h = __float2bfloat16(x);
    return *reinterpret_cast<short*>(&h);
}

// ---------------- in-degree count ----------------
__global__ __launch_bounds__(256) void k_count(const int* __restrict__ ei, int* __restrict__ counts)
{
    int e = blockIdx.x*256 + threadIdx.x;
    if (e >= EE) return;
    atomicAdd(&counts[ei[EE+e]], 1);
}

// ---------------- exclusive scan over counts -> rowptr (single block) ----------------
__global__ __launch_bounds__(1024) void k_scan(const int* __restrict__ counts, int* __restrict__ rowptr)
{
    __shared__ int sh[1024];
    const int CH = (NN + 1023)/1024;  // 49
    int t = threadIdx.x;
    int start = t*CH;
    int end = min(start+CH, NN);
    int s = 0;
    for (int i=start; i<end; i++) s += counts[i];
    sh[t] = s; __syncthreads();
    for (int off=1; off<1024; off<<=1){
        int v = (t>=off) ? sh[t-off] : 0;
        __syncthreads();
        sh[t] += v;
        __syncthreads();
    }
    int run = sh[t] - s;   // exclusive prefix
    for (int i=start; i<end; i++){ rowptr[i] = run; run += counts[i]; }
    if (t==1023) rowptr[NN] = run;
}

// ---------------- CSR fill: geometry + edge inputs in dst-sorted order ----------------
__global__ __launch_bounds__(256) void k_fill(
    const int* __restrict__ ei, const float* __restrict__ pos, const float* __restrict__ eattr,
    const int* __restrict__ rowptr, int* __restrict__ cursor,
    int* __restrict__ esrc, float* __restrict__ ein8)
{
    int e = blockIdx.x*256 + threadIdx.x;
    if (e >= EE) return;
    int src = ei[e], dst = ei[EE+e];
    float dx = pos[dst*3+0]-pos[src*3+0];
    float dy = pos[dst*3+1]-pos[src*3+1];
    float dz = pos[dst*3+2]-pos[src*3+2];
    float d = sqrtf(dx*dx+dy*dy+dz*dz+EPSF);
    float inv = 1.0f/d;
    int slot = rowptr[dst] + atomicAdd(&cursor[dst], 1);
    esrc[slot] = src;
    float4* p = (float4*)(ein8 + (size_t)slot*8);
    p[0] = make_float4(d, eattr[e*4+0], eattr[e*4+1], eattr[e*4+2]);
    p[1] = make_float4(eattr[e*4+3], dx*inv, dy*inv, dz*inv);
}

// ---------------- node embedding (fp32 master + packed bf16 gather copy) ----------------
__global__ __launch_bounds__(256) void k_embed(
    const float* __restrict__ x, const float* __restrict__ pos,
    const float* __restrict__ W_es, const float* __restrict__ b_es,
    const float* __restrict__ W_ev,
    float* __restrict__ ns, float* __restrict__ nv, __hip_bfloat16* __restrict__ nbf)
{
    int tid = blockIdx.x*256 + threadIdx.x;
    if (tid >= NN*FF) return;
    int n = tid >> 5, f = tid & 31;
    float x0=x[n*5+0], x1=x[n*5+1], x2=x[n*5+2], x3=x[n*5+3], x4=x[n*5+4];
    float s  = b_es[f] + x0*W_es[f] + x1*W_es[32+f] + x2*W_es[64+f] + x3*W_es[96+f] + x4*W_es[128+f];
    float vm =           x0*W_ev[f] + x1*W_ev[32+f] + x2*W_ev[64+f] + x3*W_ev[96+f] + x4*W_ev[128+f];
    float v0 = vm*pos[n*3+0], v1 = vm*pos[n*3+1], v2 = vm*pos[n*3+2];
    ns[tid] = s;
    nv[n*96+f*3+0] = v0;
    nv[n*96+f*3+1] = v1;
    nv[n*96+f*3+2] = v2;
    nbf[n*128+f] = __float2bfloat16(s);
    nbf[n*128+32+f*3+0] = __float2bfloat16(v0);
    nbf[n*128+32+f*3+1] = __float2bfloat16(v1);
    nbf[n*128+32+f*3+2] = __float2bfloat16(v2);
}

// ---------------- W2 transpose -> bf16: [l][k(64)][j(96)] -> [l][j(96)][k(64)] ----------------
__global__ __launch_bounds__(256) void k_transpose(const float* __restrict__ W2, __hip_bfloat16* __restrict__ W2bf)
{
    int tid = blockIdx.x*256 + threadIdx.x;
    if (tid >= NLAYERS*6144) return;
    int l = tid / 6144; int r = tid - l*6144;
    int j = r >> 6; int k = r & 63;
    W2bf[l*6144 + j*64 + k] = __float2bfloat16(W2[l*6144 + k*96 + j]);
}

// ---------------- edge MLP via MFMA -> bf16 h rows [E][96] (edge-major) ----------------
// Block = 256 thr = 4 waves, 16 edges/wave. Lane l: hidden[k] for edge (l&15),
// k = s*32 + (l>>4)*8 + j == A-frag layout. 12 MFMAs/wave.
// C staged in LDS [64 edges][100] (stride 100: 4S%32==8 -> conflict-free C writes),
// then 8B-chunk cooperative store: 64 edges x 192B fully coalesced, edge-major.
__global__ __launch_bounds__(256) void k_mlp_mfma(
    const float* __restrict__ ein8,
    const float* __restrict__ W1l, const float* __restrict__ b1l,
    const __hip_bfloat16* __restrict__ W2bfl, const float* __restrict__ b2l,
    __hip_bfloat16* __restrict__ hbuf)
{
    __shared__ __hip_bfloat16 cstage[64][100];
    const int tid  = threadIdx.x;
    const int lane = tid & 63;
    const int wave = tid >> 6;
    const int m    = lane & 15;
    const int quad = lane >> 4;
    const long long blockbase = (long long)blockIdx.x * 64;
    const long long edge = blockbase + wave*16 + m;

    const float4* p = (const float4*)(ein8 + edge*8);
    float4 q0 = p[0], q1 = p[1];
    float e0=q0.x, e1=q0.y, e2=q0.z, e3=q0.w, e4=q1.x;

    // layer-1 straight into A-fragments
    short8 afrag[2];
    #pragma unroll
    for (int s=0;s<2;s++){
        #pragma unroll
        for (int j=0;j<8;j++){
            int k = s*32 + quad*8 + j;
            float a = b1l[k] + e0*W1l[k] + e1*W1l[64+k] + e2*W1l[128+k]
                             + e3*W1l[192+k] + e4*W1l[256+k];
            afrag[s][j] = f2bf_s(elu_f(a));
        }
    }

    f32x4 acc[6];
    #pragma unroll
    for (int t=0;t<6;t++) acc[t] = (f32x4){0.f,0.f,0.f,0.f};

    #pragma unroll
    for (int s=0;s<2;s++){
        #pragma unroll
        for (int t=0;t<6;t++){
            int n = t*16 + m;
            short8 bfrag = *(const short8*)(W2bfl + n*64 + s*32 + quad*8);
            acc[t] = __builtin_amdgcn_mfma_f32_16x16x32_bf16(afrag[s], bfrag, acc[t], 0, 0, 0);
        }
    }

    // C layout: row(edge-in-tile)=quad*4+reg, col(n)=t*16+(lane&15)
    #pragma unroll
    for (int t=0;t<6;t++){
        int n = t*16 + m;
        float bias = b2l[n];
        #pragma unroll
        for (int r=0;r<4;r++){
            cstage[wave*16 + quad*4 + r][n] = __float2bfloat16(acc[t][r] + bias);
        }
    }
    __syncthreads();

    // cooperative edge-major store: 64 rows x 96 bf16 = 1536 8B-chunks
    #pragma unroll
    for (int it=0; it<6; it++){
        int flat = it*256 + tid;
        int e = flat / 24, seg = flat % 24;
        float2 val = *(const float2*)&cstage[e][seg*4];
        *(float2*)(hbuf + (blockbase + e)*96 + seg*4) = val;
    }
}

// ---------------- CSR gather-aggregate + node update (no atomics) ----------------
// hbuf edge-major: 192B contiguous per slot. Gather from packed bf16 nodes: 256B/edge.
__global__ __launch_bounds__(256) void k_agg(
    const int* __restrict__ rowptr, const int* __restrict__ esrc,
    const float* __restrict__ ein8, const __hip_bfloat16* __restrict__ hbuf,
    const float* __restrict__ nsi, const float* __restrict__ nvi,
    const __hip_bfloat16* __restrict__ nbfi,
    const float* __restrict__ Wsl, const float* __restrict__ Wvl,
    float* __restrict__ nso, float* __restrict__ nvo, __hip_bfloat16* __restrict__ nbfo)
{
    int tid = blockIdx.x*256 + threadIdx.x;
    int n = tid >> 5, f = tid & 31;
    if (n >= NN) return;
    int beg = rowptr[n], end = rowptr[n+1];
    float as=0.f, a0=0.f, a1=0.f, a2=0.f;
    for (int slot=beg; slot<end; slot++){
        const __hip_bfloat16* hr = hbuf + (size_t)slot*96;
        float gs  = __bfloat162float(hr[f]);
        float gv  = __bfloat162float(hr[32+f]);
        float gsv = __bfloat162float(hr[64+f]);
        int src = esrc[slot];
        float4 q1 = *(const float4*)(ein8 + (size_t)slot*8 + 4);
        float u0 = q1.y, u1 = q1.z, u2 = q1.w;
        const __hip_bfloat16* nb = nbfi + (size_t)src*128;
        float s  = __bfloat162float(nb[f]);
        float v0 = __bfloat162float(nb[32+f*3+0]);
        float v1 = __bfloat162float(nb[32+f*3+1]);
        float v2 = __bfloat162float(nb[32+f*3+2]);
        float c = gsv*s;
        as += gs*s;
        a0 += gv*v0 + c*u0;
        a1 += gv*v1 + c*u1;
        a2 += gv*v2 + c*u2;
    }
    float inv = 1.f/fmaxf((float)(end-beg), 1.f);
    as*=inv; a0*=inv; a1*=inv; a2*=inv;
    float os=0.f, o0=0.f, o1=0.f, o2=0.f;
    #pragma unroll
    for (int k=0;k<FF;k++){
        float bs = __shfl(as, k, 32);
        float b0 = __shfl(a0, k, 32);
        float b1 = __shfl(a1, k, 32);
        float b2 = __shfl(a2, k, 32);
        float ws = Wsl[k*32+f];
        float wv = Wvl[k*32+f];
        os += bs*ws; o0 += b0*wv; o1 += b1*wv; o2 += b2*wv;
    }
    float sn = nsi[n*32+f] + elu_f(os);
    float w0 = nvi[n*96+f*3+0] + o0;
    float w1 = nvi[n*96+f*3+1] + o1;
    float w2 = nvi[n*96+f*3+2] + o2;
    nso[n*32+f] = sn;
    nvo[n*96+f*3+0] = w0;
    nvo[n*96+f*3+1] = w1;
    nvo[n*96+f*3+2] = w2;
    nbfo[n*128+f] = __float2bfloat16(sn);
    nbfo[n*128+32+f*3+0] = __float2bfloat16(w0);
    nbfo[n*128+32+f*3+1] = __float2bfloat16(w1);
    nbfo[n*128+32+f*3+2] = __float2bfloat16(w2);
}

// ---------------- graph boundaries via binary search (batch is sorted) ----------------
__global__ __launch_bounds__(256) void k_gbounds(const int* __restrict__ batch, int* __restrict__ gstart)
{
    int g = blockIdx.x*256 + threadIdx.x;
    if (g > GG) return;
    int lo = 0, hi = NN;
    while (lo < hi){
        int mid = (lo+hi) >> 1;
        if (batch[mid] < g) lo = mid+1; else hi = mid;
    }
    gstart[g] = lo;
}

// ---------------- invariant map + graph mean pool (no atomics) ----------------
__global__ __launch_bounds__(128) void k_gpool(
    const int* __restrict__ gstart,
    const float* __restrict__ ns, const float* __restrict__ nv,
    const float* __restrict__ W_inv, const float* __restrict__ b_inv,
    float* __restrict__ xg)
{
    __shared__ float Wsh[64*128];
    __shared__ float feat[64];
    int g = blockIdx.x, j = threadIdx.x;
    for (int idx=j; idx<64*128; idx+=128) Wsh[idx] = W_inv[idx];
    int beg = gstart[g], end = gstart[g+1];
    float acc = 0.f;
    for (int n=beg; n<end; n++){
        __syncthreads();
        if (j < 32){
            feat[j] = ns[n*32+j];
        } else if (j < 64){
            int f = j-32;
            float v0=nv[n*96+f*3+0], v1=nv[n*96+f*3+1], v2=nv[n*96+f*3+2];
            feat[j] = sqrtf(v0*v0+v1*v1+v2*v2+EPSF);
        }
        __syncthreads();
        float a = 0.f;
        #pragma unroll
        for (int k=0;k<64;k++) a += feat[k]*Wsh[k*128+j];
        acc += a;
    }
    int cnt = end - beg;
    float cp = fmaxf((float)cnt, 1.f);
    xg[g*128+j] = acc/cp + b_inv[j]*((float)cnt/cp);
}

// ---------------- per-column mean/rstd over G rows ----------------
__global__ __launch_bounds__(256) void k_colstats(
    const float* __restrict__ in, float* __restrict__ mean, float* __restrict__ rstd)
{
    int j = blockIdx.x;
    float s=0.f, q=0.f;
    for (int g=threadIdx.x; g<GG; g+=256){
        float x = in[g*128+j];
        s += x; q += x*x;
    }
    __shared__ float rs[256], rq[256];
    rs[threadIdx.x]=s; rq[threadIdx.x]=q;
    __syncthreads();
    for (int st=128; st>0; st>>=1){
        if (threadIdx.x < st){ rs[threadIdx.x]+=rs[threadIdx.x+st]; rq[threadIdx.x]+=rq[threadIdx.x+st]; }
        __syncthreads();
    }
    if (threadIdx.x==0){
        float m = rs[0]/(float)GG;
        float v = rq[0]/(float)GG - m*m;
        mean[j]=m; rstd[j]=rsqrtf(v+1e-5f);
    }
}

// ---------------- BN1 + ELU + FC1 ----------------
__global__ __launch_bounds__(128) void k_fc1(
    const float* __restrict__ xg, const float* __restrict__ mean, const float* __restrict__ rstd,
    const float* __restrict__ g1, const float* __restrict__ be1,
    const float* __restrict__ Wf1, const float* __restrict__ bf1,
    float* __restrict__ z1)
{
    int g = blockIdx.x, j = threadIdx.x;
    __shared__ float a[128];
    float xin = xg[g*128+j];
    a[j] = elu_f((xin-mean[j])*rstd[j]*g1[j]+be1[j]);
    __syncthreads();
    float z = bf1[j];
    #pragma unroll 8
    for (int k=0;k<128;k++) z += a[k]*Wf1[k*128+j];
    z1[g*128+j] = z;
}

// ---------------- BN2 + ELU + FC2 -> out ----------------
__global__ __launch_bounds__(128) void k_out(
    const float* __restrict__ z1, const float* __restrict__ mean, const float* __restrict__ rstd,
    const float* __restrict__ g2, const float* __restrict__ be2,
    const float* __restrict__ Wf2, const float* __restrict__ bf2,
    float* __restrict__ out)
{
    int g = blockIdx.x, j = threadIdx.x;
    float a = elu_f((z1[g*128+j]-mean[j])*rstd[j]*g2[j]+be2[j]) * Wf2[j];
    __shared__ float red[128];
    red[j]=a; __syncthreads();
    for (int st=64; st>0; st>>=1){
        if (j<st) red[j]+=red[j+st];
        __syncthreads();
    }
    if (j==0) out[g] = red[0] + bf2[0];
}

extern "C" void kernel_launch(void* const* d_in, const int* in_sizes, int n_in,
                              void* d_out, int out_size, void* d_ws, size_t ws_size,
                              hipStream_t stream)
{
    const float* x      = (const float*)d_in[0];
    const float* pos    = (const float*)d_in[1];
    const int*   ei     = (const int*)d_in[2];
    const float* eattr  = (const float*)d_in[3];
    const int*   batch  = (const int*)d_in[4];
    const float* W_es   = (const float*)d_in[5];
    const float* b_es   = (const float*)d_in[6];
    const float* W_ev   = (const float*)d_in[7];
    const float* W1     = (const float*)d_in[8];
    const float* b1     = (const float*)d_in[9];
    const float* W2     = (const float*)d_in[10];
    const float* b2     = (const float*)d_in[11];
    const float* Ws     = (const float*)d_in[12];
    const float* Wv     = (const float*)d_in[13];
    const float* W_inv  = (const float*)d_in[14];
    const float* b_inv  = (const float*)d_in[15];
    const float* g1     = (const float*)d_in[16];
    const float* be1    = (const float*)d_in[17];
    const float* Wf1    = (const float*)d_in[18];
    const float* bf1    = (const float*)d_in[19];
    const float* g2     = (const float*)d_in[20];
    const float* be2    = (const float*)d_in[21];
    const float* Wf2    = (const float*)d_in[22];
    const float* bf2    = (const float*)d_in[23];
    float* out = (float*)d_out;

    // ---- workspace layout (4-byte units, 64B aligned blocks) ----
    char* base = (char*)d_ws;
    size_t off = 0;
    auto alloc = [&](size_t elems4) { // elems in 4-byte units
        void* p = base + off;
        off += ((elems4*4 + 63) & ~size_t(63));
        return p;
    };
    int*   counts = (int*)  alloc(50000);       // zeroed
    int*   cursor = (int*)  alloc(50000);       // zeroed
    size_t zero_bytes = off;
    int*   rowptr = (int*)  alloc(50001);
    int*   esrc   = (int*)  alloc(800000);
    float* ein8   = (float*)alloc(6400000);     // [E][8]: d,a0..a3,u0,u1,u2
    float* nsA    = (float*)alloc(1600000);
    float* nvA    = (float*)alloc(4800000);
    float* nsB    = (float*)alloc(1600000);
    float* nvB    = (float*)alloc(4800000);
    __hip_bfloat16* nbfA = (__hip_bfloat16*)alloc(3200000); // [N][128] bf16 packed
    __hip_bfloat16* nbfB = (__hip_bfloat16*)alloc(3200000);
    __hip_bfloat16* W2bf = (__hip_bfloat16*)alloc(12288);   // NL*96*64 bf16
    int*   gstart = (int*)  alloc(2049);
    float* xg     = (float*)alloc(262144);
    float* z1     = (float*)alloc(262144);
    float* m1     = (float*)alloc(128);
    float* r1     = (float*)alloc(128);
    float* m2     = (float*)alloc(128);
    float* r2     = (float*)alloc(128);
    __hip_bfloat16* hbuf = (__hip_bfloat16*)alloc(38400000); // [E][96] bf16 edge-major

    hipMemsetAsync(d_ws, 0, zero_bytes, stream);

    // ---- setup: CSR build + embedding + weight transpose ----
    k_count    <<<EE/256, 256, 0, stream>>>(ei, counts);
    k_scan     <<<1, 1024, 0, stream>>>(counts, rowptr);
    k_fill     <<<EE/256, 256, 0, stream>>>(ei, pos, eattr, rowptr, cursor, esrc, ein8);
    k_embed    <<<NN*FF/256, 256, 0, stream>>>(x, pos, W_es, b_es, W_ev, nsA, nvA, nbfA);
    k_transpose<<<(NLAYERS*6144+255)/256, 256, 0, stream>>>(W2, W2bf);

    // ---- message-passing layers (double-buffered node features) ----
    for (int l=0; l<NLAYERS; l++){
        const float* nsi = (l&1) ? nsB : nsA;
        const float* nvi = (l&1) ? nvB : nvA;
        const __hip_bfloat16* nbfi = (l&1) ? nbfB : nbfA;
        float* nso = (l&1) ? nsA : nsB;
        float* nvo = (l&1) ? nvA : nvB;
        __hip_bfloat16* nbfo = (l&1) ? nbfA : nbfB;
        k_mlp_mfma<<<EE/64, 256, 0, stream>>>(ein8,
            W1 + l*320, b1 + l*64, W2bf + l*6144, b2 + l*96, hbuf);
        k_agg<<<(NN*32+255)/256, 256, 0, stream>>>(rowptr, esrc, ein8, hbuf,
            nsi, nvi, nbfi, Ws + l*1024, Wv + l*1024, nso, nvo, nbfo);
    }
    // after 4 layers (even), fp32 output is in B buffers? no: l=0 writes B, l=1 writes A,
    // l=2 writes B, l=3 writes A -> final in A... wait: l=0 (even) nso=nsB; l=1 nso=nsA;
    // l=2 nso=nsB; l=3 nso=nsA. Final in A? l odd -> nso=nsA. l=3 odd -> nsA. Correct: A.

    // ---- invariant map + pooling + head ----
    k_gbounds <<<(GG+1+255)/256, 256, 0, stream>>>(batch, gstart);
    k_gpool   <<<GG, 128, 0, stream>>>(gstart, nsA, nvA, W_inv, b_inv, xg);
    k_colstats<<<128, 256, 0, stream>>>(xg, m1, r1);
    k_fc1     <<<GG, 128, 0, stream>>>(xg, m1, r1, g1, be1, Wf1, bf1, z1);
    k_colstats<<<128, 256, 0, stream>>>(z1, m2, r2);
    k_out     <<<GG, 128, 0, stream>>>(z1, m2, r2, g2, be2, Wf2, bf2, out);
}

// Round 9
// 1005.450 us; speedup vs baseline: 20.8380x; 1.2016x over previous
//
#include <hip/hip_runtime.h>
#include <hip/hip_bf16.h>
#include <math.h>

#define NN 50000
#define EE 800000
#define FF 32
#define HH 64
#define GG 2048
#define NLAYERS 4
#define EPSF 1e-6f
#define TILES 4

typedef __attribute__((ext_vector_type(8))) short short8;
typedef __attribute__((ext_vector_type(4))) float f32x4;

__device__ __forceinline__ float elu_f(float x){ return x > 0.0f ? x : __expf(x) - 1.0f; }
__device__ __forceinline__ short f2bf_s(float x){
    __hip_bfloat16 h = __float2bfloat16(x);
    return *reinterpret_cast<short*>(&h);
}
__device__ __forceinline__ float bf2f(unsigned short u){
    unsigned int w = ((unsigned int)u) << 16;
    return *reinterpret_cast<float*>(&w);
}

// ---------------- in-degree count ----------------
__global__ __launch_bounds__(256) void k_count(const int* __restrict__ ei, int* __restrict__ counts)
{
    int e = blockIdx.x*256 + threadIdx.x;
    if (e >= EE) return;
    atomicAdd(&counts[ei[EE+e]], 1);
}

// ---------------- exclusive scan over counts -> rowptr (single block) ----------------
__global__ __launch_bounds__(1024) void k_scan(const int* __restrict__ counts, int* __restrict__ rowptr)
{
    __shared__ int sh[1024];
    const int CH = (NN + 1023)/1024;  // 49
    int t = threadIdx.x;
    int start = t*CH;
    int end = min(start+CH, NN);
    int s = 0;
    for (int i=start; i<end; i++) s += counts[i];
    sh[t] = s; __syncthreads();
    for (int off=1; off<1024; off<<=1){
        int v = (t>=off) ? sh[t-off] : 0;
        __syncthreads();
        sh[t] += v;
        __syncthreads();
    }
    int run = sh[t] - s;   // exclusive prefix
    for (int i=start; i<end; i++){ rowptr[i] = run; run += counts[i]; }
    if (t==1023) rowptr[NN] = run;
}

// ---------------- CSR fill: geometry + edge inputs in dst-sorted order ----------------
__global__ __launch_bounds__(256) void k_fill(
    const int* __restrict__ ei, const float* __restrict__ pos, const float* __restrict__ eattr,
    const int* __restrict__ rowptr, int* __restrict__ cursor,
    int* __restrict__ esrc, float* __restrict__ ein8)
{
    int e = blockIdx.x*256 + threadIdx.x;
    if (e >= EE) return;
    int src = ei[e], dst = ei[EE+e];
    float dx = pos[dst*3+0]-pos[src*3+0];
    float dy = pos[dst*3+1]-pos[src*3+1];
    float dz = pos[dst*3+2]-pos[src*3+2];
    float d = sqrtf(dx*dx+dy*dy+dz*dz+EPSF);
    float inv = 1.0f/d;
    int slot = rowptr[dst] + atomicAdd(&cursor[dst], 1);
    esrc[slot] = src;
    float4* p = (float4*)(ein8 + (size_t)slot*8);
    p[0] = make_float4(d, eattr[e*4+0], eattr[e*4+1], eattr[e*4+2]);
    p[1] = make_float4(eattr[e*4+3], dx*inv, dy*inv, dz*inv);
}

// ---------------- node embedding (fp32 master + packed bf16 gather copy) ----------------
__global__ __launch_bounds__(256) void k_embed(
    const float* __restrict__ x, const float* __restrict__ pos,
    const float* __restrict__ W_es, const float* __restrict__ b_es,
    const float* __restrict__ W_ev,
    float* __restrict__ ns, float* __restrict__ nv, __hip_bfloat16* __restrict__ nbf)
{
    int tid = blockIdx.x*256 + threadIdx.x;
    if (tid >= NN*FF) return;
    int n = tid >> 5, f = tid & 31;
    float x0=x[n*5+0], x1=x[n*5+1], x2=x[n*5+2], x3=x[n*5+3], x4=x[n*5+4];
    float s  = b_es[f] + x0*W_es[f] + x1*W_es[32+f] + x2*W_es[64+f] + x3*W_es[96+f] + x4*W_es[128+f];
    float vm =           x0*W_ev[f] + x1*W_ev[32+f] + x2*W_ev[64+f] + x3*W_ev[96+f] + x4*W_ev[128+f];
    float v0 = vm*pos[n*3+0], v1 = vm*pos[n*3+1], v2 = vm*pos[n*3+2];
    ns[tid] = s;
    nv[n*96+f*3+0] = v0;
    nv[n*96+f*3+1] = v1;
    nv[n*96+f*3+2] = v2;
    nbf[n*128+f] = __float2bfloat16(s);
    nbf[n*128+32+f*3+0] = __float2bfloat16(v0);
    nbf[n*128+32+f*3+1] = __float2bfloat16(v1);
    nbf[n*128+32+f*3+2] = __float2bfloat16(v2);
}

// ---------------- W2 transpose -> bf16: [l][k(64)][j(96)] -> [l][j(96)][k(64)] ----------------
__global__ __launch_bounds__(256) void k_transpose(const float* __restrict__ W2, __hip_bfloat16* __restrict__ W2bf)
{
    int tid = blockIdx.x*256 + threadIdx.x;
    if (tid >= NLAYERS*6144) return;
    int l = tid / 6144; int r = tid - l*6144;
    int j = r >> 6; int k = r & 63;
    W2bf[l*6144 + j*64 + k] = __float2bfloat16(W2[l*6144 + k*96 + j]);
}

// ---------------- edge MLP via MFMA -> bf16 h rows [E][96] (edge-major) ----------------
// TILES=4 64-edge tiles per block, double-buffered LDS C-stage, one barrier per
// tile: tile t's global stores overlap tile t+1's MLP+MFMA (R6 evidence: all
// pipes <25% busy -> per-block serial-chain bound; amortize 4x + overlap).
__global__ __launch_bounds__(256) void k_mlp_mfma(
    const float* __restrict__ ein8,
    const float* __restrict__ W1l, const float* __restrict__ b1l,
    const __hip_bfloat16* __restrict__ W2bfl, const float* __restrict__ b2l,
    __hip_bfloat16* __restrict__ hbuf)
{
    __shared__ __hip_bfloat16 cstage[2][64][100];   // 2 x 12.8 KB
    const int tid  = threadIdx.x;
    const int lane = tid & 63;
    const int wave = tid >> 6;
    const int m    = lane & 15;
    const int quad = lane >> 4;

    for (int t=0; t<TILES; t++){
        const long long blockbase = ((long long)blockIdx.x*TILES + t) * 64;
        const long long edge = blockbase + wave*16 + m;

        const float4* p = (const float4*)(ein8 + edge*8);
        float4 q0 = p[0], q1 = p[1];
        float e0=q0.x, e1=q0.y, e2=q0.z, e3=q0.w, e4=q1.x;

        // layer-1 straight into A-fragments
        short8 afrag[2];
        #pragma unroll
        for (int s=0;s<2;s++){
            #pragma unroll
            for (int j=0;j<8;j++){
                int k = s*32 + quad*8 + j;
                float a = b1l[k] + e0*W1l[k] + e1*W1l[64+k] + e2*W1l[128+k]
                                 + e3*W1l[192+k] + e4*W1l[256+k];
                afrag[s][j] = f2bf_s(elu_f(a));
            }
        }

        f32x4 acc[6];
        #pragma unroll
        for (int u=0;u<6;u++) acc[u] = (f32x4){0.f,0.f,0.f,0.f};

        #pragma unroll
        for (int s=0;s<2;s++){
            #pragma unroll
            for (int u=0;u<6;u++){
                int n = u*16 + m;
                short8 bfrag = *(const short8*)(W2bfl + n*64 + s*32 + quad*8);
                acc[u] = __builtin_amdgcn_mfma_f32_16x16x32_bf16(afrag[s], bfrag, acc[u], 0, 0, 0);
            }
        }

        // C layout: row(edge-in-tile)=quad*4+reg, col(n)=u*16+(lane&15)
        __hip_bfloat16 (*cs)[100] = cstage[t&1];
        #pragma unroll
        for (int u=0;u<6;u++){
            int n = u*16 + m;
            float bias = b2l[n];
            #pragma unroll
            for (int r=0;r<4;r++){
                cs[wave*16 + quad*4 + r][n] = __float2bfloat16(acc[u][r] + bias);
            }
        }
        __syncthreads();

        // cooperative edge-major store: 64 rows x 96 bf16 = 1536 8B-chunks
        #pragma unroll
        for (int it=0; it<6; it++){
            int flat = it*256 + tid;
            int e = flat / 24, seg = flat % 24;
            float2 val = *(const float2*)&cs[e][seg*4];
            *(float2*)(hbuf + (blockbase + e)*96 + seg*4) = val;
        }
        // buffer (t&1) reusable at t+2: all waves' LDS reads complete before
        // they cross barrier t+1 (compiler drains lgkmcnt before s_barrier).
    }
}

// ---------------- CSR gather-aggregate + node update (no atomics) ----------------
// Depth-1 software pipeline: all loads for slot+1 issued before consuming slot.
// fp32 ns/nv updated IN-PLACE (each thread reads/writes only its own node n);
// only the gathered bf16 copy needs A/B double-buffering.
__global__ __launch_bounds__(256) void k_agg(
    const int* __restrict__ rowptr, const int* __restrict__ esrc,
    const float* __restrict__ ein8, const __hip_bfloat16* __restrict__ hbuf,
    float* __restrict__ ns, float* __restrict__ nv,
    const __hip_bfloat16* __restrict__ nbfi,
    const float* __restrict__ Wsl, const float* __restrict__ Wvl,
    __hip_bfloat16* __restrict__ nbfo)
{
    int tid = blockIdx.x*256 + threadIdx.x;
    int n = tid >> 5, f = tid & 31;
    if (n >= NN) return;
    int beg = rowptr[n], end = rowptr[n+1];
    float as=0.f, a0=0.f, a1=0.f, a2=0.f;
    if (beg < end){
        const unsigned short* hb = (const unsigned short*)hbuf;
        const unsigned short* nb = (const unsigned short*)nbfi;
        // stage slot = beg
        int src = esrc[beg];
        float4 u = *(const float4*)(ein8 + (size_t)beg*8 + 4);
        size_t hoff = (size_t)beg*96;
        unsigned short hx = hb[hoff+f], hy = hb[hoff+32+f], hz = hb[hoff+64+f];
        size_t noff = (size_t)src*128;
        unsigned short sb = nb[noff+f];
        unsigned short vx = nb[noff+32+f*3+0], vy = nb[noff+32+f*3+1], vz = nb[noff+32+f*3+2];
        for (int slot=beg; slot<end; slot++){
            int srcN=0; float4 uN=u;
            unsigned short hxN=0,hyN=0,hzN=0,sbN=0,vxN=0,vyN=0,vzN=0;
            if (slot+1 < end){
                srcN = esrc[slot+1];
                uN = *(const float4*)(ein8 + (size_t)(slot+1)*8 + 4);
                size_t ho = (size_t)(slot+1)*96;
                hxN = hb[ho+f]; hyN = hb[ho+32+f]; hzN = hb[ho+64+f];
                size_t no = (size_t)srcN*128;
                sbN = nb[no+f];
                vxN = nb[no+32+f*3+0]; vyN = nb[no+32+f*3+1]; vzN = nb[no+32+f*3+2];
            }
            float gs = bf2f(hx), gv = bf2f(hy), gsv = bf2f(hz);
            float s  = bf2f(sb);
            float v0 = bf2f(vx), v1 = bf2f(vy), v2 = bf2f(vz);
            float c = gsv*s;
            as += gs*s;
            a0 += gv*v0 + c*u.y;
            a1 += gv*v1 + c*u.z;
            a2 += gv*v2 + c*u.w;
            src=srcN; u=uN; hx=hxN; hy=hyN; hz=hzN; sb=sbN; vx=vxN; vy=vyN; vz=vzN;
        }
    }
    float inv = 1.f/fmaxf((float)(end-beg), 1.f);
    as*=inv; a0*=inv; a1*=inv; a2*=inv;
    float os=0.f, o0=0.f, o1=0.f, o2=0.f;
    #pragma unroll
    for (int k=0;k<FF;k++){
        float bs = __shfl(as, k, 32);
        float b0 = __shfl(a0, k, 32);
        float b1 = __shfl(a1, k, 32);
        float b2 = __shfl(a2, k, 32);
        float ws = Wsl[k*32+f];
        float wv = Wvl[k*32+f];
        os += bs*ws; o0 += b0*wv; o1 += b1*wv; o2 += b2*wv;
    }
    float sn = ns[n*32+f] + elu_f(os);
    float w0 = nv[n*96+f*3+0] + o0;
    float w1 = nv[n*96+f*3+1] + o1;
    float w2 = nv[n*96+f*3+2] + o2;
    ns[n*32+f] = sn;
    nv[n*96+f*3+0] = w0;
    nv[n*96+f*3+1] = w1;
    nv[n*96+f*3+2] = w2;
    nbfo[n*128+f] = __float2bfloat16(sn);
    nbfo[n*128+32+f*3+0] = __float2bfloat16(w0);
    nbfo[n*128+32+f*3+1] = __float2bfloat16(w1);
    nbfo[n*128+32+f*3+2] = __float2bfloat16(w2);
}

// ---------------- graph boundaries via binary search (batch is sorted) ----------------
__global__ __launch_bounds__(256) void k_gbounds(const int* __restrict__ batch, int* __restrict__ gstart)
{
    int g = blockIdx.x*256 + threadIdx.x;
    if (g > GG) return;
    int lo = 0, hi = NN;
    while (lo < hi){
        int mid = (lo+hi) >> 1;
        if (batch[mid] < g) lo = mid+1; else hi = mid;
    }
    gstart[g] = lo;
}

// ---------------- invariant map + graph mean pool (no atomics) ----------------
__global__ __launch_bounds__(128) void k_gpool(
    const int* __restrict__ gstart,
    const float* __restrict__ ns, const float* __restrict__ nv,
    const float* __restrict__ W_inv, const float* __restrict__ b_inv,
    float* __restrict__ xg)
{
    __shared__ float Wsh[64*128];
    __shared__ float feat[64];
    int g = blockIdx.x, j = threadIdx.x;
    for (int idx=j; idx<64*128; idx+=128) Wsh[idx] = W_inv[idx];
    int beg = gstart[g], end = gstart[g+1];
    float acc = 0.f;
    for (int n=beg; n<end; n++){
        __syncthreads();
        if (j < 32){
            feat[j] = ns[n*32+j];
        } else if (j < 64){
            int f = j-32;
            float v0=nv[n*96+f*3+0], v1=nv[n*96+f*3+1], v2=nv[n*96+f*3+2];
            feat[j] = sqrtf(v0*v0+v1*v1+v2*v2+EPSF);
        }
        __syncthreads();
        float a = 0.f;
        #pragma unroll
        for (int k=0;k<64;k++) a += feat[k]*Wsh[k*128+j];
        acc += a;
    }
    int cnt = end - beg;
    float cp = fmaxf((float)cnt, 1.f);
    xg[g*128+j] = acc/cp + b_inv[j]*((float)cnt/cp);
}

// ---------------- per-column mean/rstd over G rows ----------------
__global__ __launch_bounds__(256) void k_colstats(
    const float* __restrict__ in, float* __restrict__ mean, float* __restrict__ rstd)
{
    int j = blockIdx.x;
    float s=0.f, q=0.f;
    for (int g=threadIdx.x; g<GG; g+=256){
        float x = in[g*128+j];
        s += x; q += x*x;
    }
    __shared__ float rs[256], rq[256];
    rs[threadIdx.x]=s; rq[threadIdx.x]=q;
    __syncthreads();
    for (int st=128; st>0; st>>=1){
        if (threadIdx.x < st){ rs[threadIdx.x]+=rs[threadIdx.x+st]; rq[threadIdx.x]+=rq[threadIdx.x+st]; }
        __syncthreads();
    }
    if (threadIdx.x==0){
        float m = rs[0]/(float)GG;
        float v = rq[0]/(float)GG - m*m;
        mean[j]=m; rstd[j]=rsqrtf(v+1e-5f);
    }
}

// ---------------- BN1 + ELU + FC1 ----------------
__global__ __launch_bounds__(128) void k_fc1(
    const float* __restrict__ xg, const float* __restrict__ mean, const float* __restrict__ rstd,
    const float* __restrict__ g1, const float* __restrict__ be1,
    const float* __restrict__ Wf1, const float* __restrict__ bf1,
    float* __restrict__ z1)
{
    int g = blockIdx.x, j = threadIdx.x;
    __shared__ float a[128];
    float xin = xg[g*128+j];
    a[j] = elu_f((xin-mean[j])*rstd[j]*g1[j]+be1[j]);
    __syncthreads();
    float z = bf1[j];
    #pragma unroll 8
    for (int k=0;k<128;k++) z += a[k]*Wf1[k*128+j];
    z1[g*128+j] = z;
}

// ---------------- BN2 + ELU + FC2 -> out ----------------
__global__ __launch_bounds__(128) void k_out(
    const float* __restrict__ z1, const float* __restrict__ mean, const float* __restrict__ rstd,
    const float* __restrict__ g2, const float* __restrict__ be2,
    const float* __restrict__ Wf2, const float* __restrict__ bf2,
    float* __restrict__ out)
{
    int g = blockIdx.x, j = threadIdx.x;
    float a = elu_f((z1[g*128+j]-mean[j])*rstd[j]*g2[j]+be2[j]) * Wf2[j];
    __shared__ float red[128];
    red[j]=a; __syncthreads();
    for (int st=64; st>0; st>>=1){
        if (j<st) red[j]+=red[j+st];
        __syncthreads();
    }
    if (j==0) out[g] = red[0] + bf2[0];
}

extern "C" void kernel_launch(void* const* d_in, const int* in_sizes, int n_in,
                              void* d_out, int out_size, void* d_ws, size_t ws_size,
                              hipStream_t stream)
{
    const float* x      = (const float*)d_in[0];
    const float* pos    = (const float*)d_in[1];
    const int*   ei     = (const int*)d_in[2];
    const float* eattr  = (const float*)d_in[3];
    const int*   batch  = (const int*)d_in[4];
    const float* W_es   = (const float*)d_in[5];
    const float* b_es   = (const float*)d_in[6];
    const float* W_ev   = (const float*)d_in[7];
    const float* W1     = (const float*)d_in[8];
    const float* b1     = (const float*)d_in[9];
    const float* W2     = (const float*)d_in[10];
    const float* b2     = (const float*)d_in[11];
    const float* Ws     = (const float*)d_in[12];
    const float* Wv     = (const float*)d_in[13];
    const float* W_inv  = (const float*)d_in[14];
    const float* b_inv  = (const float*)d_in[15];
    const float* g1     = (const float*)d_in[16];
    const float* be1    = (const float*)d_in[17];
    const float* Wf1    = (const float*)d_in[18];
    const float* bf1    = (const float*)d_in[19];
    const float* g2     = (const float*)d_in[20];
    const float* be2    = (const float*)d_in[21];
    const float* Wf2    = (const float*)d_in[22];
    const float* bf2    = (const float*)d_in[23];
    float* out = (float*)d_out;

    // ---- workspace layout (4-byte units, 64B aligned blocks) ----
    // Total ~236.4 MB; must stay under ~256 MiB (R7 post-mortem).
    // R8 post-mortem: nbfA/nbfB are [N][128] bf16 = 12.8 MB = 3,200,000 UNITS
    // (units are 4 B) — R8's alloc(1600000) halved them -> overruns -> absmax 4.89.
    char* base = (char*)d_ws;
    size_t off = 0;
    auto alloc = [&](size_t elems4) { // elems in 4-byte units
        void* p = base + off;
        off += ((elems4*4 + 63) & ~size_t(63));
        return p;
    };
    int*   counts = (int*)  alloc(50000);       // zeroed
    int*   cursor = (int*)  alloc(50000);       // zeroed
    size_t zero_bytes = off;
    int*   rowptr = (int*)  alloc(50001);
    int*   esrc   = (int*)  alloc(800000);
    float* ein8   = (float*)alloc(6400000);     // [E][8]: d,a0..a3 | a3,u0,u1,u2
    float* ns     = (float*)alloc(1600000);     // fp32 master, in-place residual
    float* nv     = (float*)alloc(4800000);
    __hip_bfloat16* nbfA = (__hip_bfloat16*)alloc(3200000); // [N][128] bf16 = 12.8 MB
    __hip_bfloat16* nbfB = (__hip_bfloat16*)alloc(3200000);
    __hip_bfloat16* W2bf = (__hip_bfloat16*)alloc(12288);   // NL*96*64 bf16
    int*   gstart = (int*)  alloc(2049);
    float* xg     = (float*)alloc(262144);
    float* z1     = (float*)alloc(262144);
    float* m1     = (float*)alloc(128);
    float* r1     = (float*)alloc(128);
    float* m2     = (float*)alloc(128);
    float* r2     = (float*)alloc(128);
    __hip_bfloat16* hbuf = (__hip_bfloat16*)alloc(38400000); // [E][96] bf16 edge-major

    hipMemsetAsync(d_ws, 0, zero_bytes, stream);

    // ---- setup: CSR build + embedding + weight transpose ----
    k_count    <<<EE/256, 256, 0, stream>>>(ei, counts);
    k_scan     <<<1, 1024, 0, stream>>>(counts, rowptr);
    k_fill     <<<EE/256, 256, 0, stream>>>(ei, pos, eattr, rowptr, cursor, esrc, ein8);
    k_embed    <<<NN*FF/256, 256, 0, stream>>>(x, pos, W_es, b_es, W_ev, ns, nv, nbfA);
    k_transpose<<<(NLAYERS*6144+255)/256, 256, 0, stream>>>(W2, W2bf);

    // ---- message-passing layers (bf16 gather copy double-buffered) ----
    for (int l=0; l<NLAYERS; l++){
        const __hip_bfloat16* nbfi = (l&1) ? nbfB : nbfA;
        __hip_bfloat16* nbfo = (l&1) ? nbfA : nbfB;
        k_mlp_mfma<<<EE/(64*TILES), 256, 0, stream>>>(ein8,
            W1 + l*320, b1 + l*64, W2bf + l*6144, b2 + l*96, hbuf);
        k_agg<<<(NN*32+255)/256, 256, 0, stream>>>(rowptr, esrc, ein8, hbuf,
            ns, nv, nbfi, Ws + l*1024, Wv + l*1024, nbfo);
    }
    // fp32 ns/nv hold final node features (in-place updates)

    // ---- invariant map + pooling + head ----
    k_gbounds <<<(GG+1+255)/256, 256, 0, stream>>>(batch, gstart);
    k_gpool   <<<GG, 128, 0, stream>>>(gstart, ns, nv, W_inv, b_inv, xg);
    k_colstats<<<128, 256, 0, stream>>>(xg, m1, r1);
    k_fc1     <<<GG, 128, 0, stream>>>(xg, m1, r1, g1, be1, Wf1, bf1, z1);
    k_colstats<<<128, 256, 0, stream>>>(z1, m2, r2);
    k_out     <<<GG, 128, 0, stream>>>(z1, m2, r2, g2, be2, Wf2, bf2, out);
}